// Round 10
// baseline (205.603 us; speedup 1.0000x reference)
//
#include <hip/hip_runtime.h>

// MambaSkipConnection: B=4, C=192, H=W=64 (L=4096), DI=384, N=16, RK=12, DCONV=4
// Round 10: scan passes: exp2 path (Av2 pre-scaled), chunkA = exp2(Av2*sum(de)),
// mask-fma select, T14 async-stage split. conv3: reg-prefetch of next ci-tile.

#define Bn 4
#define Cn 192
#define Hn 64
#define Wn 64
#define Ln 4096
#define DIn 384
#define Nst 16
#define RK 12
#define E2 768
#define NCn 64
#define EPSf 1e-5f

typedef __bf16 bf16x8 __attribute__((ext_vector_type(8)));
typedef float f32x4 __attribute__((ext_vector_type(4)));
typedef unsigned short u16;
typedef unsigned int u32;

static __device__ __forceinline__ float sigmoidf_(float v) {
    return 1.f / (1.f + __expf(-v));
}
static __device__ __forceinline__ float softplusf_(float v) {
    return v > 15.f ? v : __logf(1.f + __expf(v));
}
static __device__ __forceinline__ u16 f2bf(float f) {
    u32 u = __float_as_uint(f);
    u32 r = (u + 0x7FFFu + ((u >> 16) & 1u)) >> 16;
    return (u16)r;
}
static __device__ __forceinline__ float bf2f(u16 v) {
    return __uint_as_float(((u32)v) << 16);
}
static __device__ __forceinline__ float fexp2(float x) {
#if __has_builtin(__builtin_amdgcn_exp2f)
    return __builtin_amdgcn_exp2f(x);
#else
    return __expf(x * 0.69314718056f);
#endif
}
static __device__ __forceinline__ float quad_sum_dpp(float p) {
    float a = __int_as_float(__builtin_amdgcn_mov_dpp(__float_as_int(p), 0xB1, 0xF, 0xF, true));
    p += a;
    float b = __int_as_float(__builtin_amdgcn_mov_dpp(__float_as_int(p), 0x4E, 0xF, 0xF, true));
    return p + b;
}
static __device__ __forceinline__ void async16(const u16* g, u16* l) {
    __builtin_amdgcn_global_load_lds((__attribute__((address_space(1))) void*)g,
                                     (__attribute__((address_space(3))) void*)l, 16, 0, 0);
}

// ---------------------------------------------------------------- K0: weight prep
__global__ __launch_bounds__(256) void k_prep(const float* __restrict__ rfw,
                                              const float* __restrict__ xpw,
                                              const float* __restrict__ dtw,
                                              const float* __restrict__ inpw,
                                              const float* __restrict__ Wo,
                                              u16* __restrict__ wcv,
                                              u16* __restrict__ wcomb_bf,
                                              u16* __restrict__ inpw_bf,
                                              u16* __restrict__ wo_bf) {
    int g = blockIdx.x * 256 + threadIdx.x;
    if (g < 331776) {
        int tap = g / 36864;
        int rem = g - tap * 36864;
        int co = rem / Cn, ci = rem - co * Cn;
        wcv[g] = f2bf(rfw[((size_t)co * Cn + ci) * 9 + tap]);
    } else if (g < 503808) {
        int i = g - 331776;
        int row = i / 384, k = i - row * 384;
        float v = 0.f;
        if (row < 384) {
#pragma unroll
            for (int r = 0; r < RK; ++r)
                v = fmaf(dtw[row * RK + r], xpw[r * 384 + k], v);
        } else if (row < 416) {
            v = xpw[(RK + row - 384) * 384 + k];
        }
        wcomb_bf[i] = f2bf(v);
    } else if (g < 651264) {
        int i = g - 503808;
        inpw_bf[i] = f2bf(inpw[i]);
    } else if (g < 724992) {
        int i = g - 651264;
        wo_bf[i] = f2bf(Wo[i]);
    }
}

// ---------------------------------------------------------------- K1: LayerNorm -> bf16 tokens
__global__ __launch_bounds__(256) void k_ln(const float* __restrict__ x,
                                            const float* __restrict__ lnw,
                                            const float* __restrict__ lnb,
                                            u16* __restrict__ tn_bf) {
    __shared__ float tile[Cn][65];
    __shared__ float red[2][4][64];
    __shared__ float mean_s[64], rstd_s[64];
    int b = blockIdx.x >> 6;
    int l0 = (blockIdx.x & 63) << 6;
    int tid = threadIdx.x;
    for (int idx = tid; idx < Cn * 64; idx += 256) {
        int c = idx >> 6, ll = idx & 63;
        tile[c][ll] = x[((size_t)(b * Cn + c) << 12) + l0 + ll];
    }
    __syncthreads();
    int ll = tid & 63, grp = tid >> 6;
    float s = 0.f, s2 = 0.f;
    for (int c = grp * 48; c < grp * 48 + 48; ++c) {
        float v = tile[c][ll];
        s += v; s2 += v * v;
    }
    red[0][grp][ll] = s; red[1][grp][ll] = s2;
    __syncthreads();
    if (tid < 64) {
        float m = red[0][0][tid] + red[0][1][tid] + red[0][2][tid] + red[0][3][tid];
        float q = red[1][0][tid] + red[1][1][tid] + red[1][2][tid] + red[1][3][tid];
        m *= (1.f / Cn);
        float var = q * (1.f / Cn) - m * m;
        mean_s[tid] = m;
        rstd_s[tid] = rsqrtf(var + EPSf);
    }
    __syncthreads();
    for (int idx = tid; idx < 64 * Cn; idx += 256) {
        int t = idx / Cn, c = idx - t * Cn;
        float v = (tile[c][t] - mean_s[t]) * rstd_s[t] * lnw[c] + lnb[c];
        tn_bf[(size_t)(b * Ln + l0 + t) * Cn + c] = f2bf(v);
    }
}

// ---------------------------------------------------------------- K2: bf16 GEMM (BM=BN=64, BK=64, async dbuf)
template <int K, int KT, int EPI, int NB, int LDO>
__global__ __launch_bounds__(256) void k_gemm3(const u16* __restrict__ A,
                                               const u16* __restrict__ W,
                                               const float* __restrict__ auxf,
                                               const u16* __restrict__ auxb,
                                               void* __restrict__ out1,
                                               float* __restrict__ out2) {
    __shared__ __align__(16) u16 As[2][64 * 64];
    __shared__ __align__(16) u16 Ws[2][64 * 64];
    int bid = blockIdx.x;
    int q = gridDim.x >> 3;
    int wk = (bid & 7) * q + (bid >> 3);
    int n0 = (wk % NB) << 6;
    int m0 = (wk / NB) << 6;
    int tid = threadIdx.x;
    int wid = tid >> 6, lane = tid & 63;
    int lrow = lane & 15, koct = lane >> 4;
    int sw = lrow & 7;
    int i0 = (wid << 7) + lane;
    int r0 = i0 >> 3, g0 = (i0 & 7) ^ (r0 & 7);
    int i1 = i0 + 64;
    int r1 = i1 >> 3, g1 = (i1 & 7) ^ (r1 & 7);
    const u16* a0p = A + (size_t)(m0 + r0) * K + g0 * 8;
    const u16* a1p = A + (size_t)(m0 + r1) * K + g1 * 8;
    const u16* w0p = W + (size_t)(n0 + r0) * K + g0 * 8;
    const u16* w1p = W + (size_t)(n0 + r1) * K + g1 * 8;
    int lb0 = (wid << 7) << 3;
    int lb1 = lb0 + 512;
    f32x4 acc[4];
#pragma unroll
    for (int j = 0; j < 4; ++j) acc[j] = (f32x4){0.f, 0.f, 0.f, 0.f};

    async16(a0p, &As[0][lb0]); async16(a1p, &As[0][lb1]);
    async16(w0p, &Ws[0][lb0]); async16(w1p, &Ws[0][lb1]);
    __syncthreads();
    for (int kt = 0; kt < KT; ++kt) {
        int cur = kt & 1;
        if (kt + 1 < KT) {
            int kk = (kt + 1) << 6;
            async16(a0p + kk, &As[cur ^ 1][lb0]);
            async16(a1p + kk, &As[cur ^ 1][lb1]);
            async16(w0p + kk, &Ws[cur ^ 1][lb0]);
            async16(w1p + kk, &Ws[cur ^ 1][lb1]);
        }
#pragma unroll
        for (int ks = 0; ks < 2; ++ks) {
            int p8 = (((ks << 2) + koct) ^ sw) << 3;
            bf16x8 a  = *(const bf16x8*)&As[cur][(((wid << 4) + lrow) << 6) + p8];
            bf16x8 b0 = *(const bf16x8*)&Ws[cur][(lrow << 6) + p8];
            bf16x8 b1 = *(const bf16x8*)&Ws[cur][((16 + lrow) << 6) + p8];
            bf16x8 b2 = *(const bf16x8*)&Ws[cur][((32 + lrow) << 6) + p8];
            bf16x8 b3 = *(const bf16x8*)&Ws[cur][((48 + lrow) << 6) + p8];
            acc[0] = __builtin_amdgcn_mfma_f32_16x16x32_bf16(a, b0, acc[0], 0, 0, 0);
            acc[1] = __builtin_amdgcn_mfma_f32_16x16x32_bf16(a, b1, acc[1], 0, 0, 0);
            acc[2] = __builtin_amdgcn_mfma_f32_16x16x32_bf16(a, b2, acc[2], 0, 0, 0);
            acc[3] = __builtin_amdgcn_mfma_f32_16x16x32_bf16(a, b3, acc[3], 0, 0, 0);
        }
        __syncthreads();
    }
    int mrow = m0 + (wid << 4) + (koct << 2);
#pragma unroll
    for (int nf = 0; nf < 4; ++nf) {
        int col = n0 + (nf << 4) + lrow;
        if constexpr (EPI == 0) {
            u16* o = (u16*)out1;
#pragma unroll
            for (int r = 0; r < 4; ++r)
                o[(size_t)(mrow + r) * LDO + col] = f2bf(acc[nf][r]);
        } else if constexpr (EPI == 1) {
            if (col < 384) {
                float dtbc = auxf[col];
                u32* dedux = (u32*)out1;
#pragma unroll
                for (int r = 0; r < 4; ++r) {
                    int m = mrow + r;
                    float de = softplusf_(acc[nf][r] + dtbc);
                    float u = bf2f(auxb[(size_t)m * DIn + col]);
                    dedux[(size_t)m * DIn + col] = (u32)f2bf(de) | ((u32)f2bf(de * u) << 16);
                }
            } else if (col < 416) {
#pragma unroll
                for (int r = 0; r < 4; ++r)
                    out2[(size_t)(mrow + r) * 32 + (col - 384)] = acc[nf][r];
            }
        } else {
            u16* t2 = (u16*)out1;
#pragma unroll
            for (int r = 0; r < 4; ++r) {
                int m = mrow + r;
                int b = m >> 12, l = m & 4095;
                float v = acc[nf][r] + auxf[((size_t)(b * Cn + col) << 12) + l];
                t2[(size_t)m * Cn + col] = f2bf(v);
            }
        }
    }
}

// ---------------------------------------------------------------- K3: causal depthwise conv1d + SiLU
__global__ __launch_bounds__(256) void k_conv1d(const u16* __restrict__ xz,
                                                const float* __restrict__ cw,
                                                const float* __restrict__ cb,
                                                u16* __restrict__ xt_bf) {
    int g = blockIdx.x * 256 + threadIdx.x;
    int m = g / 96, dq = g - m * 96;
    int d = dq << 2;
    int l = m & (Ln - 1);
    float w_[4][4];
    *(float4*)&w_[0][0] = *(const float4*)&cw[(d + 0) << 2];
    *(float4*)&w_[1][0] = *(const float4*)&cw[(d + 1) << 2];
    *(float4*)&w_[2][0] = *(const float4*)&cw[(d + 2) << 2];
    *(float4*)&w_[3][0] = *(const float4*)&cw[(d + 3) << 2];
    float4 bv = *(const float4*)&cb[d];
    float o_[4] = {bv.x, bv.y, bv.z, bv.w};
    const u16* base = xz + (size_t)m * E2 + d;
#pragma unroll
    for (int j = 0; j < 4; ++j) {
        if (l >= j) {
            ushort4 in4 = *(const ushort4*)(base - (size_t)j * E2);
            o_[0] += bf2f(in4.x) * w_[0][3 - j];
            o_[1] += bf2f(in4.y) * w_[1][3 - j];
            o_[2] += bf2f(in4.z) * w_[2][3 - j];
            o_[3] += bf2f(in4.w) * w_[3][3 - j];
        }
    }
    ushort4 rb;
    rb.x = f2bf(o_[0] * sigmoidf_(o_[0]));
    rb.y = f2bf(o_[1] * sigmoidf_(o_[1]));
    rb.z = f2bf(o_[2] * sigmoidf_(o_[2]));
    rb.w = f2bf(o_[3] * sigmoidf_(o_[3]));
    *(ushort4*)&xt_bf[(size_t)m * DIn + d] = rb;
}

// ---------------------------------------------------------------- K6a: scan pass 1 (exp2, sum-de chunkA, prefetch)
__global__ __launch_bounds__(256) void k_scan1(const u32* __restrict__ dedux,
                                               const float* __restrict__ bc,
                                               const float* __restrict__ alog,
                                               float* __restrict__ chunkA,
                                               float* __restrict__ chunkH) {
    __shared__ __align__(16) float ds_de[16][20], ds_dux[16][20], ds_bt[16][20];
    int dg = blockIdx.x, c = blockIdx.y, b = blockIdx.z;
    int tid = threadIdx.x;
    int dl = tid >> 4, n = tid & 15;
    int trow = dl, dd = n;
    float Av2 = -__expf(alog[(dg * 16 + dl) * Nst + n]) * 1.44269504f;
    float h = 0.f, sde = 0.f;
    int row0 = b * Ln + c * 64 + trow;
    u32 vN = dedux[(size_t)row0 * DIn + dg * 16 + dd];
    float bN = bc[(size_t)row0 * 32 + dd];
    for (int sub = 0; sub < 4; ++sub) {
        ds_de[dd][trow] = bf2f((u16)(vN & 0xffffu));
        ds_dux[dd][trow] = bf2f((u16)(vN >> 16));
        ds_bt[dd][trow] = bN;
        __syncthreads();
        if (sub < 3) {
            int row = row0 + (sub + 1) * 16;
            vN = dedux[(size_t)row * DIn + dg * 16 + dd];
            bN = bc[(size_t)row * 32 + dd];
        }
#pragma unroll
        for (int t4 = 0; t4 < 4; ++t4) {
            f32x4 de4 = *(const f32x4*)&ds_de[dl][t4 * 4];
            f32x4 dux4 = *(const f32x4*)&ds_dux[dl][t4 * 4];
            f32x4 bb4 = *(const f32x4*)&ds_bt[n][t4 * 4];
#pragma unroll
            for (int j = 0; j < 4; ++j) {
                float a = fexp2(de4[j] * Av2);
                sde += de4[j];
                h = fmaf(a, h, dux4[j] * bb4[j]);
            }
        }
        __syncthreads();
    }
    size_t base = (size_t)(b * NCn + c) * (DIn * Nst) + dg * 256;
    chunkA[base + tid] = fexp2(Av2 * sde);
    chunkH[base + tid] = h;
}

// ---------------------------------------------------------------- K6b: scan pass 1.5
__global__ __launch_bounds__(256) void k_scan15(const float* __restrict__ chunkA,
                                                const float* __restrict__ chunkH,
                                                float* __restrict__ hstart) {
    int dg = blockIdx.x, b = blockIdx.y;
    int tid = threadIdx.x;
    size_t off = (size_t)b * NCn * (DIn * Nst) + dg * 256 + tid;
    float h = 0.f;
    for (int c0 = 0; c0 < NCn; c0 += 8) {
        float Ar[8], Hr[8];
#pragma unroll
        for (int j = 0; j < 8; ++j) {
            Ar[j] = chunkA[off + (size_t)(c0 + j) * (DIn * Nst)];
            Hr[j] = chunkH[off + (size_t)(c0 + j) * (DIn * Nst)];
        }
#pragma unroll
        for (int j = 0; j < 8; ++j) {
            hstart[off + (size_t)(c0 + j) * (DIn * Nst)] = h;
            h = fmaf(Ar[j], h, Hr[j]);
        }
    }
}

// ---------------------------------------------------------------- K6c: scan pass 2 (exp2, mask-fma, prefetch)
__global__ __launch_bounds__(256) void k_scan2(const u32* __restrict__ dedux,
                                               const float* __restrict__ bc,
                                               const float* __restrict__ alog,
                                               const float* __restrict__ hstart,
                                               const u16* __restrict__ xt_bf,
                                               const u16* __restrict__ xz,
                                               const float* __restrict__ Dp,
                                               u16* __restrict__ agate) {
    __shared__ __align__(16) float ds_de[16][20], ds_dux[16][20], ds_bt[16][20], ds_ct[16][20];
    __shared__ __align__(16) float pq[16][16][4];
    int dg = blockIdx.x, c = blockIdx.y, b = blockIdx.z;
    int tid = threadIdx.x;
    int dl = tid >> 4, n = tid & 15;
    int trow = dl, dd = n;
    int aq = n >> 2, bq = n & 3;
    float Av2 = -__expf(alog[(dg * 16 + dl) * Nst + n]) * 1.44269504f;
    float Dr = Dp[dg * 16 + dd];
    float msk[4];
#pragma unroll
    for (int j = 0; j < 4; ++j) msk[j] = (bq == j) ? 1.f : 0.f;
    size_t base = (size_t)(b * NCn + c) * (DIn * Nst) + dg * 256;
    float h = hstart[base + tid];
    int row0 = b * Ln + c * 64 + trow;
    u32 vN = dedux[(size_t)row0 * DIn + dg * 16 + dd];
    float bN = bc[(size_t)row0 * 32 + dd];
    float cN = bc[(size_t)row0 * 32 + 16 + dd];
    u16 uN = xt_bf[(size_t)row0 * DIn + dg * 16 + dd];
    u16 zN = xz[(size_t)row0 * E2 + DIn + dg * 16 + dd];
    for (int sub = 0; sub < 4; ++sub) {
        int row = row0 + sub * 16;
        size_t doff = (size_t)row * DIn + dg * 16 + dd;
        ds_de[dd][trow] = bf2f((u16)(vN & 0xffffu));
        ds_dux[dd][trow] = bf2f((u16)(vN >> 16));
        ds_bt[dd][trow] = bN;
        ds_ct[dd][trow] = cN;
        float uu = bf2f(uN), zz = bf2f(zN);
        __syncthreads();
        if (sub < 3) {
            int rown = row0 + (sub + 1) * 16;
            vN = dedux[(size_t)rown * DIn + dg * 16 + dd];
            bN = bc[(size_t)rown * 32 + dd];
            cN = bc[(size_t)rown * 32 + 16 + dd];
            uN = xt_bf[(size_t)rown * DIn + dg * 16 + dd];
            zN = xz[(size_t)rown * E2 + DIn + dg * 16 + dd];
        }
        float P[4] = {0.f, 0.f, 0.f, 0.f};
#pragma unroll
        for (int t4 = 0; t4 < 4; ++t4) {
            f32x4 de4 = *(const f32x4*)&ds_de[dl][t4 * 4];
            f32x4 dux4 = *(const f32x4*)&ds_dux[dl][t4 * 4];
            f32x4 bb4 = *(const f32x4*)&ds_bt[n][t4 * 4];
            f32x4 ct4 = *(const f32x4*)&ds_ct[n][t4 * 4];
#pragma unroll
            for (int j = 0; j < 4; ++j) {
                float a = fexp2(de4[j] * Av2);
                h = fmaf(a, h, dux4[j] * bb4[j]);
                float p = quad_sum_dpp(h * ct4[j]);
                P[t4] = fmaf(msk[j], p, P[t4]);
            }
        }
#pragma unroll
        for (int tt = 0; tt < 4; ++tt)
            pq[tt * 4 + bq][dl][aq] = P[tt];
        __syncthreads();
        f32x4 p4 = *(const f32x4*)&pq[trow][dd][0];
        float y = (p4[0] + p4[1]) + (p4[2] + p4[3]);
        float ga = (y + uu * Dr) * (zz * sigmoidf_(zz));
        agate[doff] = f2bf(ga);
    }
}

// ---------------------------------------------------------------- K8: conv3x3 + BN + ReLU (bf16 MFMA, reg-prefetch)
__global__ __launch_bounds__(256) void k_conv3(const u16* __restrict__ t2bf,
                                               const u16* __restrict__ wcv,
                                               const float* __restrict__ rfb,
                                               const float* __restrict__ bnw,
                                               const float* __restrict__ bnb,
                                               const float* __restrict__ bnm,
                                               const float* __restrict__ bnv,
                                               float* __restrict__ out) {
    __shared__ __align__(16) u16 in_s[4 * 66 * 40];
    __shared__ __align__(16) u16 w_s[9 * 64 * 40];
    int mt = blockIdx.x;
    int n0 = blockIdx.y << 6;
    int b = mt >> 5;
    int h0 = (mt & 31) << 1;
    int hw0 = h0 << 6;
    int tid = threadIdx.x;
    int wid = tid >> 6, lane = tid & 63;
    int lrow = lane & 15, lk8 = (lane >> 4) << 3, l4 = (lane >> 4) << 2;

    for (int idx = tid; idx < 4 * 40; idx += 256) {
        int rl = idx / 40, k = idx - rl * 40;
        in_s[(rl * 66 + 0) * 40 + k] = 0;
        in_s[(rl * 66 + 65) * 40 + k] = 0;
    }

    int s0 = wid * 32 + lrow;
    int s1 = s0 + 16;
    int abase0 = ((s0 >> 6) * 66 + (s0 & 63)) * 40 + lk8;
    int abase1 = ((s1 >> 6) * 66 + (s1 & 63)) * 40 + lk8;
    int bbase = lrow * 40 + lk8;

    f32x4 acc[2][4];
#pragma unroll
    for (int i = 0; i < 2; ++i)
#pragma unroll
        for (int j = 0; j < 4; ++j) acc[i][j] = (f32x4){0.f, 0.f, 0.f, 0.f};

    int wq = tid >> 2, cq = (tid & 3) << 3;
    uint4 rin[4], rw[9];
#pragma unroll
    for (int rl = 0; rl < 4; ++rl) {
        int gr = h0 - 1 + rl;
        rin[rl] = make_uint4(0u, 0u, 0u, 0u);
        if (gr >= 0 && gr < Hn)
            rin[rl] = *(const uint4*)&t2bf[(size_t)((b << 12) + (gr << 6) + wq) * Cn + cq];
    }
#pragma unroll
    for (int tap = 0; tap < 9; ++tap)
        rw[tap] = *(const uint4*)&wcv[((size_t)tap * Cn + n0 + wq) * Cn + cq];

    for (int ci0 = 0; ci0 < Cn; ci0 += 32) {
#pragma unroll
        for (int rl = 0; rl < 4; ++rl)
            *(uint4*)&in_s[(rl * 66 + wq + 1) * 40 + cq] = rin[rl];
#pragma unroll
        for (int tap = 0; tap < 9; ++tap)
            *(uint4*)&w_s[(tap * 64 + wq) * 40 + cq] = rw[tap];
        __syncthreads();
        if (ci0 + 32 < Cn) {
            int cin = ci0 + 32;
#pragma unroll
            for (int rl = 0; rl < 4; ++rl) {
                int gr = h0 - 1 + rl;
                rin[rl] = make_uint4(0u, 0u, 0u, 0u);
                if (gr >= 0 && gr < Hn)
                    rin[rl] = *(const uint4*)&t2bf[(size_t)((b << 12) + (gr << 6) + wq) * Cn + cin + cq];
            }
#pragma unroll
            for (int tap = 0; tap < 9; ++tap)
                rw[tap] = *(const uint4*)&wcv[((size_t)tap * Cn + n0 + wq) * Cn + cin + cq];
        }
#pragma unroll
        for (int kh = 0; kh < 3; ++kh) {
#pragma unroll
            for (int kw = 0; kw < 3; ++kw) {
                int aoff = (kh * 66 + kw) * 40;
                bf16x8 a0 = *(const bf16x8*)&in_s[abase0 + aoff];
                bf16x8 a1 = *(const bf16x8*)&in_s[abase1 + aoff];
                int boff = (kh * 3 + kw) * 2560;
#pragma unroll
                for (int nf = 0; nf < 4; ++nf) {
                    bf16x8 bb = *(const bf16x8*)&w_s[bbase + nf * 640 + boff];
                    acc[0][nf] = __builtin_amdgcn_mfma_f32_16x16x32_bf16(a0, bb, acc[0][nf], 0, 0, 0);
                    acc[1][nf] = __builtin_amdgcn_mfma_f32_16x16x32_bf16(a1, bb, acc[1][nf], 0, 0, 0);
                }
            }
        }
        __syncthreads();
    }
#pragma unroll
    for (int nf = 0; nf < 4; ++nf) {
        int co = n0 + nf * 16 + lrow;
        float sc = bnw[co] * rsqrtf(bnv[co] + EPSf);
        float sf = (rfb[co] - bnm[co]) * sc + bnb[co];
        size_t obase = ((size_t)(b * Cn + co) << 12) + hw0;
#pragma unroll
        for (int mf = 0; mf < 2; ++mf) {
            int sb = wid * 32 + mf * 16 + l4;
            float4 o;
            o.x = fmaxf(acc[mf][nf][0] * sc + sf, 0.f);
            o.y = fmaxf(acc[mf][nf][1] * sc + sf, 0.f);
            o.z = fmaxf(acc[mf][nf][2] * sc + sf, 0.f);
            o.w = fmaxf(acc[mf][nf][3] * sc + sf, 0.f);
            *(float4*)&out[obase + sb] = o;
        }
    }
}

// ----------------------------------------------------------------
extern "C" void kernel_launch(void* const* d_in, const int* in_sizes, int n_in,
                              void* d_out, int out_size, void* d_ws, size_t ws_size,
                              hipStream_t stream) {
    const float* x    = (const float*)d_in[0];
    const float* lnw  = (const float*)d_in[1];
    const float* lnb  = (const float*)d_in[2];
    const float* inpw = (const float*)d_in[3];
    const float* cw   = (const float*)d_in[4];
    const float* cb   = (const float*)d_in[5];
    const float* xpw  = (const float*)d_in[6];
    const float* dtw  = (const float*)d_in[7];
    const float* dtb  = (const float*)d_in[8];
    const float* alog = (const float*)d_in[9];
    const float* Dp   = (const float*)d_in[10];
    const float* Wo   = (const float*)d_in[11];
    const float* rfw  = (const float*)d_in[12];
    const float* rfb  = (const float*)d_in[13];
    const float* bnw  = (const float*)d_in[14];
    const float* bnb  = (const float*)d_in[15];
    const float* bnm  = (const float*)d_in[16];
    const float* bnv  = (const float*)d_in[17];

    float* ws = (float*)d_ws;
    u16* tn_bf    = (u16*)ws;
    u16* t2bf     = (u16*)ws;
    float* hstart = ws + 1572864;
    u16* xz       = (u16*)(ws + 3145728);
    u16* xt_bf    = (u16*)(ws + 9437184);
    u32* dedux    = (u32*)(ws + 12582912);
    float* bc     = ws + 18874368;
    u16* agate    = (u16*)(ws + 19398656);
    float* chunkA = ws + 22544384;
    float* chunkH = ws + 24117248;
    u16* wcv      = (u16*)(ws + 25690112);
    u16* wcomb_bf = (u16*)(ws + 25856000);
    u16* inpw_bf  = (u16*)(ws + 25942016);
    u16* wo_bf    = (u16*)(ws + 26015744);

    k_prep<<<2832, 256, 0, stream>>>(rfw, xpw, dtw, inpw, Wo, wcv, wcomb_bf, inpw_bf, wo_bf);
    k_ln<<<Bn * (Ln / 64), 256, 0, stream>>>(x, lnw, lnb, tn_bf);
    k_gemm3<Cn, 3, 0, 12, E2><<<(Bn * Ln / 64) * 12, 256, 0, stream>>>(
        tn_bf, inpw_bf, nullptr, nullptr, xz, nullptr);
    k_conv1d<<<(Bn * Ln * (DIn / 4)) / 256, 256, 0, stream>>>(xz, cw, cb, xt_bf);
    k_gemm3<DIn, 6, 1, 7, 0><<<(Bn * Ln / 64) * 7, 256, 0, stream>>>(
        xt_bf, wcomb_bf, dtb, xt_bf, dedux, bc);
    k_scan1<<<dim3(DIn / 16, NCn, Bn), 256, 0, stream>>>(dedux, bc, alog, chunkA, chunkH);
    k_scan15<<<dim3(DIn / 16, Bn), 256, 0, stream>>>(chunkA, chunkH, hstart);
    k_scan2<<<dim3(DIn / 16, NCn, Bn), 256, 0, stream>>>(dedux, bc, alog, hstart,
                                                         xt_bf, xz, Dp, agate);
    k_gemm3<DIn, 6, 2, 3, Cn><<<(Bn * Ln / 64) * 3, 256, 0, stream>>>(
        agate, wo_bf, x, nullptr, t2bf, nullptr);
    k_conv3<<<dim3(128, Cn / 64), 256, 0, stream>>>(t2bf, wcv, rfb, bnw, bnb, bnm, bnv,
                                                    (float*)d_out);
}

// Round 11
// 186.391 us; speedup vs baseline: 1.1031x; 1.1031x over previous
//
#include <hip/hip_runtime.h>

// MambaSkipConnection: B=4, C=192, H=W=64 (L=4096), DI=384, N=16, RK=12, DCONV=4
// Round 11: conv3x3 rebuilt as k_gemm3-style implicit GEMM over zero-padded NHWC
// t2pad[B][66][66][192]; K=1728 (9 taps x 192 ci) via per-step pointer offsets.
// Weights repacked [co][tap*192+ci]; BN folded to scsf table in k_prep.

#define Bn 4
#define Cn 192
#define Hn 64
#define Wn 64
#define Ln 4096
#define DIn 384
#define Nst 16
#define RK 12
#define E2 768
#define NCn 64
#define EPSf 1e-5f
#define HP 66
#define HP2 4356   // 66*66

typedef __bf16 bf16x8 __attribute__((ext_vector_type(8)));
typedef float f32x4 __attribute__((ext_vector_type(4)));
typedef unsigned short u16;
typedef unsigned int u32;

static __device__ __forceinline__ float sigmoidf_(float v) {
    return 1.f / (1.f + __expf(-v));
}
static __device__ __forceinline__ float softplusf_(float v) {
    return v > 15.f ? v : __logf(1.f + __expf(v));
}
static __device__ __forceinline__ u16 f2bf(float f) {
    u32 u = __float_as_uint(f);
    u32 r = (u + 0x7FFFu + ((u >> 16) & 1u)) >> 16;
    return (u16)r;
}
static __device__ __forceinline__ float bf2f(u16 v) {
    return __uint_as_float(((u32)v) << 16);
}
static __device__ __forceinline__ float fexp2(float x) {
#if __has_builtin(__builtin_amdgcn_exp2f)
    return __builtin_amdgcn_exp2f(x);
#else
    return __expf(x * 0.69314718056f);
#endif
}
static __device__ __forceinline__ float quad_sum_dpp(float p) {
    float a = __int_as_float(__builtin_amdgcn_mov_dpp(__float_as_int(p), 0xB1, 0xF, 0xF, true));
    p += a;
    float b = __int_as_float(__builtin_amdgcn_mov_dpp(__float_as_int(p), 0x4E, 0xF, 0xF, true));
    return p + b;
}
static __device__ __forceinline__ void async16(const u16* g, u16* l) {
    __builtin_amdgcn_global_load_lds((__attribute__((address_space(1))) void*)g,
                                     (__attribute__((address_space(3))) void*)l, 16, 0, 0);
}

// ---------------------------------------------------------------- K0: weight prep
// [0,331776) wcv2[co][tap*192+ci] ; [331776,503808) wcomb_bf (448x384) ;
// [503808,651264) inpw_bf ; [651264,724992) wo_bf ; [724992,725376) scsf
__global__ __launch_bounds__(256) void k_prep(const float* __restrict__ rfw,
                                              const float* __restrict__ xpw,
                                              const float* __restrict__ dtw,
                                              const float* __restrict__ inpw,
                                              const float* __restrict__ Wo,
                                              const float* __restrict__ rfb,
                                              const float* __restrict__ bnw,
                                              const float* __restrict__ bnb,
                                              const float* __restrict__ bnm,
                                              const float* __restrict__ bnv,
                                              u16* __restrict__ wcv2,
                                              u16* __restrict__ wcomb_bf,
                                              u16* __restrict__ inpw_bf,
                                              u16* __restrict__ wo_bf,
                                              float* __restrict__ scsf) {
    int g = blockIdx.x * 256 + threadIdx.x;
    if (g < 331776) {
        int co = g / 1728;
        int rem = g - co * 1728;
        int tap = rem / Cn, ci = rem - tap * Cn;
        wcv2[g] = f2bf(rfw[((size_t)co * Cn + ci) * 9 + tap]);
    } else if (g < 503808) {
        int i = g - 331776;
        int row = i / 384, k = i - row * 384;
        float v = 0.f;
        if (row < 384) {
#pragma unroll
            for (int r = 0; r < RK; ++r)
                v = fmaf(dtw[row * RK + r], xpw[r * 384 + k], v);
        } else if (row < 416) {
            v = xpw[(RK + row - 384) * 384 + k];
        }
        wcomb_bf[i] = f2bf(v);
    } else if (g < 651264) {
        int i = g - 503808;
        inpw_bf[i] = f2bf(inpw[i]);
    } else if (g < 724992) {
        int i = g - 651264;
        wo_bf[i] = f2bf(Wo[i]);
    } else if (g < 725376) {
        int i = g - 724992;
        if (i < 192) {
            scsf[i] = bnw[i] * rsqrtf(bnv[i] + EPSf);
        } else {
            int c = i - 192;
            float sc = bnw[c] * rsqrtf(bnv[c] + EPSf);
            scsf[i] = (rfb[c] - bnm[c]) * sc + bnb[c];
        }
    }
}

// ---------------------------------------------------------------- K1: LayerNorm -> bf16 tokens
__global__ __launch_bounds__(256) void k_ln(const float* __restrict__ x,
                                            const float* __restrict__ lnw,
                                            const float* __restrict__ lnb,
                                            u16* __restrict__ tn_bf) {
    __shared__ float tile[Cn][65];
    __shared__ float red[2][4][64];
    __shared__ float mean_s[64], rstd_s[64];
    int b = blockIdx.x >> 6;
    int l0 = (blockIdx.x & 63) << 6;
    int tid = threadIdx.x;
    for (int idx = tid; idx < Cn * 64; idx += 256) {
        int c = idx >> 6, ll = idx & 63;
        tile[c][ll] = x[((size_t)(b * Cn + c) << 12) + l0 + ll];
    }
    __syncthreads();
    int ll = tid & 63, grp = tid >> 6;
    float s = 0.f, s2 = 0.f;
    for (int c = grp * 48; c < grp * 48 + 48; ++c) {
        float v = tile[c][ll];
        s += v; s2 += v * v;
    }
    red[0][grp][ll] = s; red[1][grp][ll] = s2;
    __syncthreads();
    if (tid < 64) {
        float m = red[0][0][tid] + red[0][1][tid] + red[0][2][tid] + red[0][3][tid];
        float q = red[1][0][tid] + red[1][1][tid] + red[1][2][tid] + red[1][3][tid];
        m *= (1.f / Cn);
        float var = q * (1.f / Cn) - m * m;
        mean_s[tid] = m;
        rstd_s[tid] = rsqrtf(var + EPSf);
    }
    __syncthreads();
    for (int idx = tid; idx < 64 * Cn; idx += 256) {
        int t = idx / Cn, c = idx - t * Cn;
        float v = (tile[c][t] - mean_s[t]) * rstd_s[t] * lnw[c] + lnb[c];
        tn_bf[(size_t)(b * Ln + l0 + t) * Cn + c] = f2bf(v);
    }
}

// ---------------------------------------------------------------- K2: bf16 GEMM (BM=BN=64, BK=64, async dbuf)
// EPI 0: bf16 out (LDO). EPI 1: proj epilogue. EPI 2: +residual -> t2pad (padded NHWC).
template <int K, int KT, int EPI, int NB, int LDO>
__global__ __launch_bounds__(256) void k_gemm3(const u16* __restrict__ A,
                                               const u16* __restrict__ W,
                                               const float* __restrict__ auxf,
                                               const u16* __restrict__ auxb,
                                               void* __restrict__ out1,
                                               float* __restrict__ out2) {
    __shared__ __align__(16) u16 As[2][64 * 64];
    __shared__ __align__(16) u16 Ws[2][64 * 64];
    int bid = blockIdx.x;
    int q = gridDim.x >> 3;
    int wk = (bid & 7) * q + (bid >> 3);
    int n0 = (wk % NB) << 6;
    int m0 = (wk / NB) << 6;
    int tid = threadIdx.x;
    int wid = tid >> 6, lane = tid & 63;
    int lrow = lane & 15, koct = lane >> 4;
    int sw = lrow & 7;
    int i0 = (wid << 7) + lane;
    int r0 = i0 >> 3, g0 = (i0 & 7) ^ (r0 & 7);
    int i1 = i0 + 64;
    int r1 = i1 >> 3, g1 = (i1 & 7) ^ (r1 & 7);
    const u16* a0p = A + (size_t)(m0 + r0) * K + g0 * 8;
    const u16* a1p = A + (size_t)(m0 + r1) * K + g1 * 8;
    const u16* w0p = W + (size_t)(n0 + r0) * K + g0 * 8;
    const u16* w1p = W + (size_t)(n0 + r1) * K + g1 * 8;
    int lb0 = (wid << 7) << 3;
    int lb1 = lb0 + 512;
    f32x4 acc[4];
#pragma unroll
    for (int j = 0; j < 4; ++j) acc[j] = (f32x4){0.f, 0.f, 0.f, 0.f};

    async16(a0p, &As[0][lb0]); async16(a1p, &As[0][lb1]);
    async16(w0p, &Ws[0][lb0]); async16(w1p, &Ws[0][lb1]);
    __syncthreads();
    for (int kt = 0; kt < KT; ++kt) {
        int cur = kt & 1;
        if (kt + 1 < KT) {
            int kk = (kt + 1) << 6;
            async16(a0p + kk, &As[cur ^ 1][lb0]);
            async16(a1p + kk, &As[cur ^ 1][lb1]);
            async16(w0p + kk, &Ws[cur ^ 1][lb0]);
            async16(w1p + kk, &Ws[cur ^ 1][lb1]);
        }
#pragma unroll
        for (int ks = 0; ks < 2; ++ks) {
            int p8 = (((ks << 2) + koct) ^ sw) << 3;
            bf16x8 a  = *(const bf16x8*)&As[cur][(((wid << 4) + lrow) << 6) + p8];
            bf16x8 b0 = *(const bf16x8*)&Ws[cur][(lrow << 6) + p8];
            bf16x8 b1 = *(const bf16x8*)&Ws[cur][((16 + lrow) << 6) + p8];
            bf16x8 b2 = *(const bf16x8*)&Ws[cur][((32 + lrow) << 6) + p8];
            bf16x8 b3 = *(const bf16x8*)&Ws[cur][((48 + lrow) << 6) + p8];
            acc[0] = __builtin_amdgcn_mfma_f32_16x16x32_bf16(a, b0, acc[0], 0, 0, 0);
            acc[1] = __builtin_amdgcn_mfma_f32_16x16x32_bf16(a, b1, acc[1], 0, 0, 0);
            acc[2] = __builtin_amdgcn_mfma_f32_16x16x32_bf16(a, b2, acc[2], 0, 0, 0);
            acc[3] = __builtin_amdgcn_mfma_f32_16x16x32_bf16(a, b3, acc[3], 0, 0, 0);
        }
        __syncthreads();
    }
    int mrow = m0 + (wid << 4) + (koct << 2);
#pragma unroll
    for (int nf = 0; nf < 4; ++nf) {
        int col = n0 + (nf << 4) + lrow;
        if constexpr (EPI == 0) {
            u16* o = (u16*)out1;
#pragma unroll
            for (int r = 0; r < 4; ++r)
                o[(size_t)(mrow + r) * LDO + col] = f2bf(acc[nf][r]);
        } else if constexpr (EPI == 1) {
            if (col < 384) {
                float dtbc = auxf[col];
                u32* dedux = (u32*)out1;
#pragma unroll
                for (int r = 0; r < 4; ++r) {
                    int m = mrow + r;
                    float de = softplusf_(acc[nf][r] + dtbc);
                    float u = bf2f(auxb[(size_t)m * DIn + col]);
                    dedux[(size_t)m * DIn + col] = (u32)f2bf(de) | ((u32)f2bf(de * u) << 16);
                }
            } else if (col < 416) {
#pragma unroll
                for (int r = 0; r < 4; ++r)
                    out2[(size_t)(mrow + r) * 32 + (col - 384)] = acc[nf][r];
            }
        } else {
            u16* t2 = (u16*)out1;
#pragma unroll
            for (int r = 0; r < 4; ++r) {
                int m = mrow + r;
                int b = m >> 12, l = m & 4095;
                int h = l >> 6, w = l & 63;
                float v = acc[nf][r] + auxf[((size_t)(b * Cn + col) << 12) + l];
                t2[(size_t)(b * HP2 + (h + 1) * HP + (w + 1)) * Cn + col] = f2bf(v);
            }
        }
    }
}

// ---------------------------------------------------------------- K3: causal depthwise conv1d + SiLU
__global__ __launch_bounds__(256) void k_conv1d(const u16* __restrict__ xz,
                                                const float* __restrict__ cw,
                                                const float* __restrict__ cb,
                                                u16* __restrict__ xt_bf) {
    int g = blockIdx.x * 256 + threadIdx.x;
    int m = g / 96, dq = g - m * 96;
    int d = dq << 2;
    int l = m & (Ln - 1);
    float w_[4][4];
    *(float4*)&w_[0][0] = *(const float4*)&cw[(d + 0) << 2];
    *(float4*)&w_[1][0] = *(const float4*)&cw[(d + 1) << 2];
    *(float4*)&w_[2][0] = *(const float4*)&cw[(d + 2) << 2];
    *(float4*)&w_[3][0] = *(const float4*)&cw[(d + 3) << 2];
    float4 bv = *(const float4*)&cb[d];
    float o_[4] = {bv.x, bv.y, bv.z, bv.w};
    const u16* base = xz + (size_t)m * E2 + d;
#pragma unroll
    for (int j = 0; j < 4; ++j) {
        if (l >= j) {
            ushort4 in4 = *(const ushort4*)(base - (size_t)j * E2);
            o_[0] += bf2f(in4.x) * w_[0][3 - j];
            o_[1] += bf2f(in4.y) * w_[1][3 - j];
            o_[2] += bf2f(in4.z) * w_[2][3 - j];
            o_[3] += bf2f(in4.w) * w_[3][3 - j];
        }
    }
    ushort4 rb;
    rb.x = f2bf(o_[0] * sigmoidf_(o_[0]));
    rb.y = f2bf(o_[1] * sigmoidf_(o_[1]));
    rb.z = f2bf(o_[2] * sigmoidf_(o_[2]));
    rb.w = f2bf(o_[3] * sigmoidf_(o_[3]));
    *(ushort4*)&xt_bf[(size_t)m * DIn + d] = rb;
}

// ---------------------------------------------------------------- K6a: scan pass 1
__global__ __launch_bounds__(256) void k_scan1(const u32* __restrict__ dedux,
                                               const float* __restrict__ bc,
                                               const float* __restrict__ alog,
                                               float* __restrict__ chunkA,
                                               float* __restrict__ chunkH) {
    __shared__ __align__(16) float ds_de[16][20], ds_dux[16][20], ds_bt[16][20];
    int dg = blockIdx.x, c = blockIdx.y, b = blockIdx.z;
    int tid = threadIdx.x;
    int dl = tid >> 4, n = tid & 15;
    int trow = dl, dd = n;
    float Av2 = -__expf(alog[(dg * 16 + dl) * Nst + n]) * 1.44269504f;
    float h = 0.f, sde = 0.f;
    int row0 = b * Ln + c * 64 + trow;
    u32 vN = dedux[(size_t)row0 * DIn + dg * 16 + dd];
    float bN = bc[(size_t)row0 * 32 + dd];
    for (int sub = 0; sub < 4; ++sub) {
        ds_de[dd][trow] = bf2f((u16)(vN & 0xffffu));
        ds_dux[dd][trow] = bf2f((u16)(vN >> 16));
        ds_bt[dd][trow] = bN;
        __syncthreads();
        if (sub < 3) {
            int row = row0 + (sub + 1) * 16;
            vN = dedux[(size_t)row * DIn + dg * 16 + dd];
            bN = bc[(size_t)row * 32 + dd];
        }
#pragma unroll
        for (int t4 = 0; t4 < 4; ++t4) {
            f32x4 de4 = *(const f32x4*)&ds_de[dl][t4 * 4];
            f32x4 dux4 = *(const f32x4*)&ds_dux[dl][t4 * 4];
            f32x4 bb4 = *(const f32x4*)&ds_bt[n][t4 * 4];
#pragma unroll
            for (int j = 0; j < 4; ++j) {
                float a = fexp2(de4[j] * Av2);
                sde += de4[j];
                h = fmaf(a, h, dux4[j] * bb4[j]);
            }
        }
        __syncthreads();
    }
    size_t base = (size_t)(b * NCn + c) * (DIn * Nst) + dg * 256;
    chunkA[base + tid] = fexp2(Av2 * sde);
    chunkH[base + tid] = h;
}

// ---------------------------------------------------------------- K6b: scan pass 1.5
__global__ __launch_bounds__(256) void k_scan15(const float* __restrict__ chunkA,
                                                const float* __restrict__ chunkH,
                                                float* __restrict__ hstart) {
    int dg = blockIdx.x, b = blockIdx.y;
    int tid = threadIdx.x;
    size_t off = (size_t)b * NCn * (DIn * Nst) + dg * 256 + tid;
    float h = 0.f;
    for (int c0 = 0; c0 < NCn; c0 += 8) {
        float Ar[8], Hr[8];
#pragma unroll
        for (int j = 0; j < 8; ++j) {
            Ar[j] = chunkA[off + (size_t)(c0 + j) * (DIn * Nst)];
            Hr[j] = chunkH[off + (size_t)(c0 + j) * (DIn * Nst)];
        }
#pragma unroll
        for (int j = 0; j < 8; ++j) {
            hstart[off + (size_t)(c0 + j) * (DIn * Nst)] = h;
            h = fmaf(Ar[j], h, Hr[j]);
        }
    }
}

// ---------------------------------------------------------------- K6c: scan pass 2 (gate fused)
__global__ __launch_bounds__(256) void k_scan2(const u32* __restrict__ dedux,
                                               const float* __restrict__ bc,
                                               const float* __restrict__ alog,
                                               const float* __restrict__ hstart,
                                               const u16* __restrict__ xt_bf,
                                               const u16* __restrict__ xz,
                                               const float* __restrict__ Dp,
                                               u16* __restrict__ agate) {
    __shared__ __align__(16) float ds_de[16][20], ds_dux[16][20], ds_bt[16][20], ds_ct[16][20];
    __shared__ __align__(16) float pq[16][16][4];
    int dg = blockIdx.x, c = blockIdx.y, b = blockIdx.z;
    int tid = threadIdx.x;
    int dl = tid >> 4, n = tid & 15;
    int trow = dl, dd = n;
    int aq = n >> 2, bq = n & 3;
    float Av2 = -__expf(alog[(dg * 16 + dl) * Nst + n]) * 1.44269504f;
    float Dr = Dp[dg * 16 + dd];
    float msk[4];
#pragma unroll
    for (int j = 0; j < 4; ++j) msk[j] = (bq == j) ? 1.f : 0.f;
    size_t base = (size_t)(b * NCn + c) * (DIn * Nst) + dg * 256;
    float h = hstart[base + tid];
    int row0 = b * Ln + c * 64 + trow;
    u32 vN = dedux[(size_t)row0 * DIn + dg * 16 + dd];
    float bN = bc[(size_t)row0 * 32 + dd];
    float cN = bc[(size_t)row0 * 32 + 16 + dd];
    u16 uN = xt_bf[(size_t)row0 * DIn + dg * 16 + dd];
    u16 zN = xz[(size_t)row0 * E2 + DIn + dg * 16 + dd];
    for (int sub = 0; sub < 4; ++sub) {
        int row = row0 + sub * 16;
        size_t doff = (size_t)row * DIn + dg * 16 + dd;
        ds_de[dd][trow] = bf2f((u16)(vN & 0xffffu));
        ds_dux[dd][trow] = bf2f((u16)(vN >> 16));
        ds_bt[dd][trow] = bN;
        ds_ct[dd][trow] = cN;
        float uu = bf2f(uN), zz = bf2f(zN);
        __syncthreads();
        if (sub < 3) {
            int rown = row0 + (sub + 1) * 16;
            vN = dedux[(size_t)rown * DIn + dg * 16 + dd];
            bN = bc[(size_t)rown * 32 + dd];
            cN = bc[(size_t)rown * 32 + 16 + dd];
            uN = xt_bf[(size_t)rown * DIn + dg * 16 + dd];
            zN = xz[(size_t)rown * E2 + DIn + dg * 16 + dd];
        }
        float P[4] = {0.f, 0.f, 0.f, 0.f};
#pragma unroll
        for (int t4 = 0; t4 < 4; ++t4) {
            f32x4 de4 = *(const f32x4*)&ds_de[dl][t4 * 4];
            f32x4 dux4 = *(const f32x4*)&ds_dux[dl][t4 * 4];
            f32x4 bb4 = *(const f32x4*)&ds_bt[n][t4 * 4];
            f32x4 ct4 = *(const f32x4*)&ds_ct[n][t4 * 4];
#pragma unroll
            for (int j = 0; j < 4; ++j) {
                float a = fexp2(de4[j] * Av2);
                h = fmaf(a, h, dux4[j] * bb4[j]);
                float p = quad_sum_dpp(h * ct4[j]);
                P[t4] = fmaf(msk[j], p, P[t4]);
            }
        }
#pragma unroll
        for (int tt = 0; tt < 4; ++tt)
            pq[tt * 4 + bq][dl][aq] = P[tt];
        __syncthreads();
        f32x4 p4 = *(const f32x4*)&pq[trow][dd][0];
        float y = (p4[0] + p4[1]) + (p4[2] + p4[3]);
        float ga = (y + uu * Dr) * (zz * sigmoidf_(zz));
        agate[doff] = f2bf(ga);
    }
}

// ---------------------------------------------------------------- K8: conv3x3 as padded implicit GEMM (K=1728)
// grid = 768 (256 image rows x 3 co-tiles). BM=64 (one image row), BN=64, 27 K-steps.
__global__ __launch_bounds__(256) void k_conv3g(const u16* __restrict__ t2pad,
                                                const u16* __restrict__ wcv2,
                                                const float* __restrict__ scsf,
                                                float* __restrict__ out) {
    __shared__ __align__(16) u16 As[2][64 * 64];
    __shared__ __align__(16) u16 Ws[2][64 * 64];
    int bid = blockIdx.x;
    int q = gridDim.x >> 3;
    int wk = (bid & 7) * q + (bid >> 3);
    int n0 = (wk % 3) << 6;
    int rowid = wk / 3;
    int b = rowid >> 6, h = rowid & 63;
    int tid = threadIdx.x;
    int wid = tid >> 6, lane = tid & 63;
    int lrow = lane & 15, koct = lane >> 4;
    int sw = lrow & 7;
    int i0 = (wid << 7) + lane;
    int r0 = i0 >> 3, g0 = (i0 & 7) ^ (r0 & 7);
    int i1 = i0 + 64;
    int r1 = i1 >> 3, g1 = (i1 & 7) ^ (r1 & 7);
    const u16* Abase = t2pad + (size_t)(b * HP2 + (h + 1) * HP + 1) * Cn;
    const u16* a0p = Abase + r0 * Cn + g0 * 8;
    const u16* a1p = Abase + r1 * Cn + g1 * 8;
    const u16* w0p = wcv2 + (size_t)(n0 + r0) * 1728 + g0 * 8;
    const u16* w1p = wcv2 + (size_t)(n0 + r1) * 1728 + g1 * 8;
    int lb0 = (wid << 7) << 3;
    int lb1 = lb0 + 512;
    const int tapoff[9] = {-HP - 1, -HP, -HP + 1, -1, 0, 1, HP - 1, HP, HP + 1};
    f32x4 acc[4];
#pragma unroll
    for (int j = 0; j < 4; ++j) acc[j] = (f32x4){0.f, 0.f, 0.f, 0.f};

    {
        int koff = tapoff[0] * Cn;
        async16(a0p + koff, &As[0][lb0]); async16(a1p + koff, &As[0][lb1]);
        async16(w0p, &Ws[0][lb0]); async16(w1p, &Ws[0][lb1]);
    }
    __syncthreads();
    for (int kt = 0; kt < 27; ++kt) {
        int cur = kt & 1;
        if (kt + 1 < 27) {
            int t = (kt + 1) / 3;
            int koff = tapoff[t] * Cn + (((kt + 1) - t * 3) << 6);
            async16(a0p + koff, &As[cur ^ 1][lb0]);
            async16(a1p + koff, &As[cur ^ 1][lb1]);
            int kw = (kt + 1) << 6;
            async16(w0p + kw, &Ws[cur ^ 1][lb0]);
            async16(w1p + kw, &Ws[cur ^ 1][lb1]);
        }
#pragma unroll
        for (int ks = 0; ks < 2; ++ks) {
            int p8 = (((ks << 2) + koct) ^ sw) << 3;
            bf16x8 a  = *(const bf16x8*)&As[cur][(((wid << 4) + lrow) << 6) + p8];
            bf16x8 b0 = *(const bf16x8*)&Ws[cur][(lrow << 6) + p8];
            bf16x8 b1 = *(const bf16x8*)&Ws[cur][((16 + lrow) << 6) + p8];
            bf16x8 b2 = *(const bf16x8*)&Ws[cur][((32 + lrow) << 6) + p8];
            bf16x8 b3 = *(const bf16x8*)&Ws[cur][((48 + lrow) << 6) + p8];
            acc[0] = __builtin_amdgcn_mfma_f32_16x16x32_bf16(a, b0, acc[0], 0, 0, 0);
            acc[1] = __builtin_amdgcn_mfma_f32_16x16x32_bf16(a, b1, acc[1], 0, 0, 0);
            acc[2] = __builtin_amdgcn_mfma_f32_16x16x32_bf16(a, b2, acc[2], 0, 0, 0);
            acc[3] = __builtin_amdgcn_mfma_f32_16x16x32_bf16(a, b3, acc[3], 0, 0, 0);
        }
        __syncthreads();
    }
    int w0_ = (wid << 4) + (koct << 2);
#pragma unroll
    for (int nf = 0; nf < 4; ++nf) {
        int col = n0 + (nf << 4) + lrow;
        float sc = scsf[col], sf = scsf[192 + col];
        float4 o;
        o.x = fmaxf(acc[nf][0] * sc + sf, 0.f);
        o.y = fmaxf(acc[nf][1] * sc + sf, 0.f);
        o.z = fmaxf(acc[nf][2] * sc + sf, 0.f);
        o.w = fmaxf(acc[nf][3] * sc + sf, 0.f);
        *(float4*)&out[((size_t)(b * Cn + col) << 12) + (h << 6) + w0_] = o;
    }
}

// ----------------------------------------------------------------
extern "C" void kernel_launch(void* const* d_in, const int* in_sizes, int n_in,
                              void* d_out, int out_size, void* d_ws, size_t ws_size,
                              hipStream_t stream) {
    const float* x    = (const float*)d_in[0];
    const float* lnw  = (const float*)d_in[1];
    const float* lnb  = (const float*)d_in[2];
    const float* inpw = (const float*)d_in[3];
    const float* cw   = (const float*)d_in[4];
    const float* cb   = (const float*)d_in[5];
    const float* xpw  = (const float*)d_in[6];
    const float* dtw  = (const float*)d_in[7];
    const float* dtb  = (const float*)d_in[8];
    const float* alog = (const float*)d_in[9];
    const float* Dp   = (const float*)d_in[10];
    const float* Wo   = (const float*)d_in[11];
    const float* rfw  = (const float*)d_in[12];
    const float* rfb  = (const float*)d_in[13];
    const float* bnw  = (const float*)d_in[14];
    const float* bnb  = (const float*)d_in[15];
    const float* bnm  = (const float*)d_in[16];
    const float* bnv  = (const float*)d_in[17];

    float* ws = (float*)d_ws;
    // region map (float slots):
    // [0 .. 1572864)          tn_bf (bf16, ln->inproj)
    // [1572864 .. 3145728)    hstart
    // [3145728 .. 9437184)    xz (bf16, 16384x768)
    // [9437184 .. 12582912)   xt_bf (bf16)
    // [12582912 .. 18874368)  dedux (u32 packed de|dux)
    // [18874368 .. 19398656)  bc (fp32, 16384x32)
    // [19398656 .. 22544384)  agate (bf16)
    // [22544384 .. 24117248)  chunkA
    // [24117248 .. 25690112)  chunkH
    // [25690112 .. 25856000)  wcv2 (bf16, 192x1728)
    // [25856000 .. 25942016)  wcomb_bf
    // [25942016 .. 26015744)  inpw_bf
    // [26015744 .. 26052608)  wo_bf
    // [26052608 .. 26052992)  scsf (fp32, 384)
    // [26053120 .. 27725824)  t2pad (bf16, 4x66x66x192)
    u16* tn_bf    = (u16*)ws;
    float* hstart = ws + 1572864;
    u16* xz       = (u16*)(ws + 3145728);
    u16* xt_bf    = (u16*)(ws + 9437184);
    u32* dedux    = (u32*)(ws + 12582912);
    float* bc     = ws + 18874368;
    u16* agate    = (u16*)(ws + 19398656);
    float* chunkA = ws + 22544384;
    float* chunkH = ws + 24117248;
    u16* wcv2     = (u16*)(ws + 25690112);
    u16* wcomb_bf = (u16*)(ws + 25856000);
    u16* inpw_bf  = (u16*)(ws + 25942016);
    u16* wo_bf    = (u16*)(ws + 26015744);
    float* scsf   = ws + 26052608;
    u16* t2pad    = (u16*)(ws + 26053120);

    hipMemsetAsync(t2pad, 0, (size_t)Bn * HP2 * Cn * sizeof(u16), stream);
    k_prep<<<2834, 256, 0, stream>>>(rfw, xpw, dtw, inpw, Wo, rfb, bnw, bnb, bnm, bnv,
                                     wcv2, wcomb_bf, inpw_bf, wo_bf, scsf);
    k_ln<<<Bn * (Ln / 64), 256, 0, stream>>>(x, lnw, lnb, tn_bf);
    k_gemm3<Cn, 3, 0, 12, E2><<<(Bn * Ln / 64) * 12, 256, 0, stream>>>(
        tn_bf, inpw_bf, nullptr, nullptr, xz, nullptr);
    k_conv1d<<<(Bn * Ln * (DIn / 4)) / 256, 256, 0, stream>>>(xz, cw, cb, xt_bf);
    k_gemm3<DIn, 6, 1, 7, 0><<<(Bn * Ln / 64) * 7, 256, 0, stream>>>(
        xt_bf, wcomb_bf, dtb, xt_bf, dedux, bc);
    k_scan1<<<dim3(DIn / 16, NCn, Bn), 256, 0, stream>>>(dedux, bc, alog, chunkA, chunkH);
    k_scan15<<<dim3(DIn / 16, Bn), 256, 0, stream>>>(chunkA, chunkH, hstart);
    k_scan2<<<dim3(DIn / 16, NCn, Bn), 256, 0, stream>>>(dedux, bc, alog, hstart,
                                                         xt_bf, xz, Dp, agate);
    k_gemm3<DIn, 6, 2, 3, Cn><<<(Bn * Ln / 64) * 3, 256, 0, stream>>>(
        agate, wo_bf, x, nullptr, (void*)t2pad, nullptr);
    k_conv3g<<<768, 256, 0, stream>>>(t2pad, wcv2, scsf, (float*)d_out);
}

// Round 12
// 181.890 us; speedup vs baseline: 1.1304x; 1.0247x over previous
//
#include <hip/hip_runtime.h>

// MambaSkipConnection: B=4, C=192, H=W=64 (L=4096), DI=384, N=16, RK=12, DCONV=4
// Round 12: scan passes: single barrier/sub via LDS ping-pong, deferred gating
// (pq double-buffer), DPP-fused quad reduction. Rest identical to round 11.

#define Bn 4
#define Cn 192
#define Hn 64
#define Wn 64
#define Ln 4096
#define DIn 384
#define Nst 16
#define RK 12
#define E2 768
#define NCn 64
#define EPSf 1e-5f
#define HP 66
#define HP2 4356   // 66*66

typedef __bf16 bf16x8 __attribute__((ext_vector_type(8)));
typedef float f32x4 __attribute__((ext_vector_type(4)));
typedef unsigned short u16;
typedef unsigned int u32;

static __device__ __forceinline__ float sigmoidf_(float v) {
    return 1.f / (1.f + __expf(-v));
}
static __device__ __forceinline__ float softplusf_(float v) {
    return v > 15.f ? v : __logf(1.f + __expf(v));
}
static __device__ __forceinline__ u16 f2bf(float f) {
    u32 u = __float_as_uint(f);
    u32 r = (u + 0x7FFFu + ((u >> 16) & 1u)) >> 16;
    return (u16)r;
}
static __device__ __forceinline__ float bf2f(u16 v) {
    return __uint_as_float(((u32)v) << 16);
}
static __device__ __forceinline__ float fexp2(float x) {
#if __has_builtin(__builtin_amdgcn_exp2f)
    return __builtin_amdgcn_exp2f(x);
#else
    return __expf(x * 0.69314718056f);
#endif
}
// fused DPP quad-sum: 2 instructions (v_add_f32 with quad_perm on src0)
static __device__ __forceinline__ float quad_sum_dpp(float p) {
    float t, r;
    asm volatile("v_add_f32 %0, %1, %1 quad_perm:[1,0,3,2] row_mask:0xf bank_mask:0xf"
                 : "=&v"(t) : "v"(p));
    asm volatile("v_add_f32 %0, %1, %1 quad_perm:[2,3,0,1] row_mask:0xf bank_mask:0xf"
                 : "=&v"(r) : "v"(t));
    return r;
}
static __device__ __forceinline__ void async16(const u16* g, u16* l) {
    __builtin_amdgcn_global_load_lds((__attribute__((address_space(1))) void*)g,
                                     (__attribute__((address_space(3))) void*)l, 16, 0, 0);
}

// ---------------------------------------------------------------- K0: weight prep
__global__ __launch_bounds__(256) void k_prep(const float* __restrict__ rfw,
                                              const float* __restrict__ xpw,
                                              const float* __restrict__ dtw,
                                              const float* __restrict__ inpw,
                                              const float* __restrict__ Wo,
                                              const float* __restrict__ rfb,
                                              const float* __restrict__ bnw,
                                              const float* __restrict__ bnb,
                                              const float* __restrict__ bnm,
                                              const float* __restrict__ bnv,
                                              u16* __restrict__ wcv2,
                                              u16* __restrict__ wcomb_bf,
                                              u16* __restrict__ inpw_bf,
                                              u16* __restrict__ wo_bf,
                                              float* __restrict__ scsf) {
    int g = blockIdx.x * 256 + threadIdx.x;
    if (g < 331776) {
        int co = g / 1728;
        int rem = g - co * 1728;
        int tap = rem / Cn, ci = rem - tap * Cn;
        wcv2[g] = f2bf(rfw[((size_t)co * Cn + ci) * 9 + tap]);
    } else if (g < 503808) {
        int i = g - 331776;
        int row = i / 384, k = i - row * 384;
        float v = 0.f;
        if (row < 384) {
#pragma unroll
            for (int r = 0; r < RK; ++r)
                v = fmaf(dtw[row * RK + r], xpw[r * 384 + k], v);
        } else if (row < 416) {
            v = xpw[(RK + row - 384) * 384 + k];
        }
        wcomb_bf[i] = f2bf(v);
    } else if (g < 651264) {
        int i = g - 503808;
        inpw_bf[i] = f2bf(inpw[i]);
    } else if (g < 724992) {
        int i = g - 651264;
        wo_bf[i] = f2bf(Wo[i]);
    } else if (g < 725376) {
        int i = g - 724992;
        if (i < 192) {
            scsf[i] = bnw[i] * rsqrtf(bnv[i] + EPSf);
        } else {
            int c = i - 192;
            float sc = bnw[c] * rsqrtf(bnv[c] + EPSf);
            scsf[i] = (rfb[c] - bnm[c]) * sc + bnb[c];
        }
    }
}

// ---------------------------------------------------------------- K1: LayerNorm -> bf16 tokens
__global__ __launch_bounds__(256) void k_ln(const float* __restrict__ x,
                                            const float* __restrict__ lnw,
                                            const float* __restrict__ lnb,
                                            u16* __restrict__ tn_bf) {
    __shared__ float tile[Cn][65];
    __shared__ float red[2][4][64];
    __shared__ float mean_s[64], rstd_s[64];
    int b = blockIdx.x >> 6;
    int l0 = (blockIdx.x & 63) << 6;
    int tid = threadIdx.x;
    for (int idx = tid; idx < Cn * 64; idx += 256) {
        int c = idx >> 6, ll = idx & 63;
        tile[c][ll] = x[((size_t)(b * Cn + c) << 12) + l0 + ll];
    }
    __syncthreads();
    int ll = tid & 63, grp = tid >> 6;
    float s = 0.f, s2 = 0.f;
    for (int c = grp * 48; c < grp * 48 + 48; ++c) {
        float v = tile[c][ll];
        s += v; s2 += v * v;
    }
    red[0][grp][ll] = s; red[1][grp][ll] = s2;
    __syncthreads();
    if (tid < 64) {
        float m = red[0][0][tid] + red[0][1][tid] + red[0][2][tid] + red[0][3][tid];
        float q = red[1][0][tid] + red[1][1][tid] + red[1][2][tid] + red[1][3][tid];
        m *= (1.f / Cn);
        float var = q * (1.f / Cn) - m * m;
        mean_s[tid] = m;
        rstd_s[tid] = rsqrtf(var + EPSf);
    }
    __syncthreads();
    for (int idx = tid; idx < 64 * Cn; idx += 256) {
        int t = idx / Cn, c = idx - t * Cn;
        float v = (tile[c][t] - mean_s[t]) * rstd_s[t] * lnw[c] + lnb[c];
        tn_bf[(size_t)(b * Ln + l0 + t) * Cn + c] = f2bf(v);
    }
}

// ---------------------------------------------------------------- K2: bf16 GEMM (BM=BN=64, BK=64, async dbuf)
template <int K, int KT, int EPI, int NB, int LDO>
__global__ __launch_bounds__(256) void k_gemm3(const u16* __restrict__ A,
                                               const u16* __restrict__ W,
                                               const float* __restrict__ auxf,
                                               const u16* __restrict__ auxb,
                                               void* __restrict__ out1,
                                               float* __restrict__ out2) {
    __shared__ __align__(16) u16 As[2][64 * 64];
    __shared__ __align__(16) u16 Ws[2][64 * 64];
    int bid = blockIdx.x;
    int q = gridDim.x >> 3;
    int wk = (bid & 7) * q + (bid >> 3);
    int n0 = (wk % NB) << 6;
    int m0 = (wk / NB) << 6;
    int tid = threadIdx.x;
    int wid = tid >> 6, lane = tid & 63;
    int lrow = lane & 15, koct = lane >> 4;
    int sw = lrow & 7;
    int i0 = (wid << 7) + lane;
    int r0 = i0 >> 3, g0 = (i0 & 7) ^ (r0 & 7);
    int i1 = i0 + 64;
    int r1 = i1 >> 3, g1 = (i1 & 7) ^ (r1 & 7);
    const u16* a0p = A + (size_t)(m0 + r0) * K + g0 * 8;
    const u16* a1p = A + (size_t)(m0 + r1) * K + g1 * 8;
    const u16* w0p = W + (size_t)(n0 + r0) * K + g0 * 8;
    const u16* w1p = W + (size_t)(n0 + r1) * K + g1 * 8;
    int lb0 = (wid << 7) << 3;
    int lb1 = lb0 + 512;
    f32x4 acc[4];
#pragma unroll
    for (int j = 0; j < 4; ++j) acc[j] = (f32x4){0.f, 0.f, 0.f, 0.f};

    async16(a0p, &As[0][lb0]); async16(a1p, &As[0][lb1]);
    async16(w0p, &Ws[0][lb0]); async16(w1p, &Ws[0][lb1]);
    __syncthreads();
    for (int kt = 0; kt < KT; ++kt) {
        int cur = kt & 1;
        if (kt + 1 < KT) {
            int kk = (kt + 1) << 6;
            async16(a0p + kk, &As[cur ^ 1][lb0]);
            async16(a1p + kk, &As[cur ^ 1][lb1]);
            async16(w0p + kk, &Ws[cur ^ 1][lb0]);
            async16(w1p + kk, &Ws[cur ^ 1][lb1]);
        }
#pragma unroll
        for (int ks = 0; ks < 2; ++ks) {
            int p8 = (((ks << 2) + koct) ^ sw) << 3;
            bf16x8 a  = *(const bf16x8*)&As[cur][(((wid << 4) + lrow) << 6) + p8];
            bf16x8 b0 = *(const bf16x8*)&Ws[cur][(lrow << 6) + p8];
            bf16x8 b1 = *(const bf16x8*)&Ws[cur][((16 + lrow) << 6) + p8];
            bf16x8 b2 = *(const bf16x8*)&Ws[cur][((32 + lrow) << 6) + p8];
            bf16x8 b3 = *(const bf16x8*)&Ws[cur][((48 + lrow) << 6) + p8];
            acc[0] = __builtin_amdgcn_mfma_f32_16x16x32_bf16(a, b0, acc[0], 0, 0, 0);
            acc[1] = __builtin_amdgcn_mfma_f32_16x16x32_bf16(a, b1, acc[1], 0, 0, 0);
            acc[2] = __builtin_amdgcn_mfma_f32_16x16x32_bf16(a, b2, acc[2], 0, 0, 0);
            acc[3] = __builtin_amdgcn_mfma_f32_16x16x32_bf16(a, b3, acc[3], 0, 0, 0);
        }
        __syncthreads();
    }
    int mrow = m0 + (wid << 4) + (koct << 2);
#pragma unroll
    for (int nf = 0; nf < 4; ++nf) {
        int col = n0 + (nf << 4) + lrow;
        if constexpr (EPI == 0) {
            u16* o = (u16*)out1;
#pragma unroll
            for (int r = 0; r < 4; ++r)
                o[(size_t)(mrow + r) * LDO + col] = f2bf(acc[nf][r]);
        } else if constexpr (EPI == 1) {
            if (col < 384) {
                float dtbc = auxf[col];
                u32* dedux = (u32*)out1;
#pragma unroll
                for (int r = 0; r < 4; ++r) {
                    int m = mrow + r;
                    float de = softplusf_(acc[nf][r] + dtbc);
                    float u = bf2f(auxb[(size_t)m * DIn + col]);
                    dedux[(size_t)m * DIn + col] = (u32)f2bf(de) | ((u32)f2bf(de * u) << 16);
                }
            } else if (col < 416) {
#pragma unroll
                for (int r = 0; r < 4; ++r)
                    out2[(size_t)(mrow + r) * 32 + (col - 384)] = acc[nf][r];
            }
        } else {
            u16* t2 = (u16*)out1;
#pragma unroll
            for (int r = 0; r < 4; ++r) {
                int m = mrow + r;
                int b = m >> 12, l = m & 4095;
                int h = l >> 6, w = l & 63;
                float v = acc[nf][r] + auxf[((size_t)(b * Cn + col) << 12) + l];
                t2[(size_t)(b * HP2 + (h + 1) * HP + (w + 1)) * Cn + col] = f2bf(v);
            }
        }
    }
}

// ---------------------------------------------------------------- K3: causal depthwise conv1d + SiLU
__global__ __launch_bounds__(256) void k_conv1d(const u16* __restrict__ xz,
                                                const float* __restrict__ cw,
                                                const float* __restrict__ cb,
                                                u16* __restrict__ xt_bf) {
    int g = blockIdx.x * 256 + threadIdx.x;
    int m = g / 96, dq = g - m * 96;
    int d = dq << 2;
    int l = m & (Ln - 1);
    float w_[4][4];
    *(float4*)&w_[0][0] = *(const float4*)&cw[(d + 0) << 2];
    *(float4*)&w_[1][0] = *(const float4*)&cw[(d + 1) << 2];
    *(float4*)&w_[2][0] = *(const float4*)&cw[(d + 2) << 2];
    *(float4*)&w_[3][0] = *(const float4*)&cw[(d + 3) << 2];
    float4 bv = *(const float4*)&cb[d];
    float o_[4] = {bv.x, bv.y, bv.z, bv.w};
    const u16* base = xz + (size_t)m * E2 + d;
#pragma unroll
    for (int j = 0; j < 4; ++j) {
        if (l >= j) {
            ushort4 in4 = *(const ushort4*)(base - (size_t)j * E2);
            o_[0] += bf2f(in4.x) * w_[0][3 - j];
            o_[1] += bf2f(in4.y) * w_[1][3 - j];
            o_[2] += bf2f(in4.z) * w_[2][3 - j];
            o_[3] += bf2f(in4.w) * w_[3][3 - j];
        }
    }
    ushort4 rb;
    rb.x = f2bf(o_[0] * sigmoidf_(o_[0]));
    rb.y = f2bf(o_[1] * sigmoidf_(o_[1]));
    rb.z = f2bf(o_[2] * sigmoidf_(o_[2]));
    rb.w = f2bf(o_[3] * sigmoidf_(o_[3]));
    *(ushort4*)&xt_bf[(size_t)m * DIn + d] = rb;
}

// ---------------------------------------------------------------- K6a: scan pass 1 (1 barrier/sub, LDS ping-pong)
__global__ __launch_bounds__(256) void k_scan1(const u32* __restrict__ dedux,
                                               const float* __restrict__ bc,
                                               const float* __restrict__ alog,
                                               float* __restrict__ chunkA,
                                               float* __restrict__ chunkH) {
    __shared__ __align__(16) float ds_de[2][16][20], ds_dux[2][16][20], ds_bt[2][16][20];
    int dg = blockIdx.x, c = blockIdx.y, b = blockIdx.z;
    int tid = threadIdx.x;
    int dl = tid >> 4, n = tid & 15;
    int trow = dl, dd = n;
    float Av2 = -__expf(alog[(dg * 16 + dl) * Nst + n]) * 1.44269504f;
    float h = 0.f, sde = 0.f;
    int row0 = b * Ln + c * 64 + trow;
    u32 vN = dedux[(size_t)row0 * DIn + dg * 16 + dd];
    float bN = bc[(size_t)row0 * 32 + dd];
    for (int sub = 0; sub < 4; ++sub) {
        int bs = sub & 1;
        ds_de[bs][dd][trow] = bf2f((u16)(vN & 0xffffu));
        ds_dux[bs][dd][trow] = bf2f((u16)(vN >> 16));
        ds_bt[bs][dd][trow] = bN;
        __syncthreads();
        if (sub < 3) {
            int row = row0 + (sub + 1) * 16;
            vN = dedux[(size_t)row * DIn + dg * 16 + dd];
            bN = bc[(size_t)row * 32 + dd];
        }
#pragma unroll
        for (int t4 = 0; t4 < 4; ++t4) {
            f32x4 de4 = *(const f32x4*)&ds_de[bs][dl][t4 * 4];
            f32x4 dux4 = *(const f32x4*)&ds_dux[bs][dl][t4 * 4];
            f32x4 bb4 = *(const f32x4*)&ds_bt[bs][n][t4 * 4];
#pragma unroll
            for (int j = 0; j < 4; ++j) {
                float a = fexp2(de4[j] * Av2);
                sde += de4[j];
                h = fmaf(a, h, dux4[j] * bb4[j]);
            }
        }
    }
    size_t base = (size_t)(b * NCn + c) * (DIn * Nst) + dg * 256;
    chunkA[base + tid] = fexp2(Av2 * sde);
    chunkH[base + tid] = h;
}

// ---------------------------------------------------------------- K6b: scan pass 1.5
__global__ __launch_bounds__(256) void k_scan15(const float* __restrict__ chunkA,
                                                const float* __restrict__ chunkH,
                                                float* __restrict__ hstart) {
    int dg = blockIdx.x, b = blockIdx.y;
    int tid = threadIdx.x;
    size_t off = (size_t)b * NCn * (DIn * Nst) + dg * 256 + tid;
    float h = 0.f;
    for (int c0 = 0; c0 < NCn; c0 += 8) {
        float Ar[8], Hr[8];
#pragma unroll
        for (int j = 0; j < 8; ++j) {
            Ar[j] = chunkA[off + (size_t)(c0 + j) * (DIn * Nst)];
            Hr[j] = chunkH[off + (size_t)(c0 + j) * (DIn * Nst)];
        }
#pragma unroll
        for (int j = 0; j < 8; ++j) {
            hstart[off + (size_t)(c0 + j) * (DIn * Nst)] = h;
            h = fmaf(Ar[j], h, Hr[j]);
        }
    }
}

// ---------------------------------------------------------------- K6c: scan pass 2 (1 barrier/sub, deferred gate)
__global__ __launch_bounds__(256) void k_scan2(const u32* __restrict__ dedux,
                                               const float* __restrict__ bc,
                                               const float* __restrict__ alog,
                                               const float* __restrict__ hstart,
                                               const u16* __restrict__ xt_bf,
                                               const u16* __restrict__ xz,
                                               const float* __restrict__ Dp,
                                               u16* __restrict__ agate) {
    __shared__ __align__(16) float ds_de[2][16][20], ds_dux[2][16][20];
    __shared__ __align__(16) float ds_bt[2][16][20], ds_ct[2][16][20];
    __shared__ __align__(16) float pq[2][16][16][4];
    int dg = blockIdx.x, c = blockIdx.y, b = blockIdx.z;
    int tid = threadIdx.x;
    int dl = tid >> 4, n = tid & 15;
    int trow = dl, dd = n;
    int aq = n >> 2, bq = n & 3;
    float Av2 = -__expf(alog[(dg * 16 + dl) * Nst + n]) * 1.44269504f;
    float Dr = Dp[dg * 16 + dd];
    float msk[4];
#pragma unroll
    for (int j = 0; j < 4; ++j) msk[j] = (bq == j) ? 1.f : 0.f;
    size_t base = (size_t)(b * NCn + c) * (DIn * Nst) + dg * 256;
    float h = hstart[base + tid];
    int row0 = b * Ln + c * 64 + trow;
    int dgoff = dg * 16 + dd;
    u32 vN = dedux[(size_t)row0 * DIn + dgoff];
    float bN = bc[(size_t)row0 * 32 + dd];
    float cN = bc[(size_t)row0 * 32 + 16 + dd];
    u16 uN = xt_bf[(size_t)row0 * DIn + dgoff];
    u16 zN = xz[(size_t)row0 * E2 + DIn + dgoff];
    float pu = 0.f, pz = 0.f;
    int prow = row0;
    for (int sub = 0; sub < 4; ++sub) {
        int bs = sub & 1;
        int row = row0 + sub * 16;
        ds_de[bs][dd][trow] = bf2f((u16)(vN & 0xffffu));
        ds_dux[bs][dd][trow] = bf2f((u16)(vN >> 16));
        ds_bt[bs][dd][trow] = bN;
        ds_ct[bs][dd][trow] = cN;
        float uu = bf2f(uN), zz = bf2f(zN);
        __syncthreads();
        if (sub < 3) {
            int rown = row0 + (sub + 1) * 16;
            vN = dedux[(size_t)rown * DIn + dgoff];
            bN = bc[(size_t)rown * 32 + dd];
            cN = bc[(size_t)rown * 32 + 16 + dd];
            uN = xt_bf[(size_t)rown * DIn + dgoff];
            zN = xz[(size_t)rown * E2 + DIn + dgoff];
        }
        if (sub > 0) {
            f32x4 p4 = *(const f32x4*)&pq[bs ^ 1][trow][dd][0];
            float y = (p4[0] + p4[1]) + (p4[2] + p4[3]);
            float ga = (y + pu * Dr) * (pz * sigmoidf_(pz));
            agate[(size_t)prow * DIn + dgoff] = f2bf(ga);
        }
        float P[4] = {0.f, 0.f, 0.f, 0.f};
#pragma unroll
        for (int t4 = 0; t4 < 4; ++t4) {
            f32x4 de4 = *(const f32x4*)&ds_de[bs][dl][t4 * 4];
            f32x4 dux4 = *(const f32x4*)&ds_dux[bs][dl][t4 * 4];
            f32x4 bb4 = *(const f32x4*)&ds_bt[bs][n][t4 * 4];
            f32x4 ct4 = *(const f32x4*)&ds_ct[bs][n][t4 * 4];
#pragma unroll
            for (int j = 0; j < 4; ++j) {
                float a = fexp2(de4[j] * Av2);
                h = fmaf(a, h, dux4[j] * bb4[j]);
                float p = quad_sum_dpp(h * ct4[j]);
                P[t4] = fmaf(msk[j], p, P[t4]);
            }
        }
#pragma unroll
        for (int tt = 0; tt < 4; ++tt)
            pq[bs][tt * 4 + bq][dl][aq] = P[tt];
        pu = uu; pz = zz; prow = row;
    }
    __syncthreads();
    {
        f32x4 p4 = *(const f32x4*)&pq[1][trow][dd][0];
        float y = (p4[0] + p4[1]) + (p4[2] + p4[3]);
        float ga = (y + pu * Dr) * (pz * sigmoidf_(pz));
        agate[(size_t)prow * DIn + dgoff] = f2bf(ga);
    }
}

// ---------------------------------------------------------------- K8: conv3x3 as padded implicit GEMM (K=1728)
__global__ __launch_bounds__(256) void k_conv3g(const u16* __restrict__ t2pad,
                                                const u16* __restrict__ wcv2,
                                                const float* __restrict__ scsf,
                                                float* __restrict__ out) {
    __shared__ __align__(16) u16 As[2][64 * 64];
    __shared__ __align__(16) u16 Ws[2][64 * 64];
    int bid = blockIdx.x;
    int q = gridDim.x >> 3;
    int wk = (bid & 7) * q + (bid >> 3);
    int n0 = (wk % 3) << 6;
    int rowid = wk / 3;
    int b = rowid >> 6, h = rowid & 63;
    int tid = threadIdx.x;
    int wid = tid >> 6, lane = tid & 63;
    int lrow = lane & 15, koct = lane >> 4;
    int sw = lrow & 7;
    int i0 = (wid << 7) + lane;
    int r0 = i0 >> 3, g0 = (i0 & 7) ^ (r0 & 7);
    int i1 = i0 + 64;
    int r1 = i1 >> 3, g1 = (i1 & 7) ^ (r1 & 7);
    const u16* Abase = t2pad + (size_t)(b * HP2 + (h + 1) * HP + 1) * Cn;
    const u16* a0p = Abase + r0 * Cn + g0 * 8;
    const u16* a1p = Abase + r1 * Cn + g1 * 8;
    const u16* w0p = wcv2 + (size_t)(n0 + r0) * 1728 + g0 * 8;
    const u16* w1p = wcv2 + (size_t)(n0 + r1) * 1728 + g1 * 8;
    int lb0 = (wid << 7) << 3;
    int lb1 = lb0 + 512;
    const int tapoff[9] = {-HP - 1, -HP, -HP + 1, -1, 0, 1, HP - 1, HP, HP + 1};
    f32x4 acc[4];
#pragma unroll
    for (int j = 0; j < 4; ++j) acc[j] = (f32x4){0.f, 0.f, 0.f, 0.f};

    {
        int koff = tapoff[0] * Cn;
        async16(a0p + koff, &As[0][lb0]); async16(a1p + koff, &As[0][lb1]);
        async16(w0p, &Ws[0][lb0]); async16(w1p, &Ws[0][lb1]);
    }
    __syncthreads();
    for (int kt = 0; kt < 27; ++kt) {
        int cur = kt & 1;
        if (kt + 1 < 27) {
            int t = (kt + 1) / 3;
            int koff = tapoff[t] * Cn + (((kt + 1) - t * 3) << 6);
            async16(a0p + koff, &As[cur ^ 1][lb0]);
            async16(a1p + koff, &As[cur ^ 1][lb1]);
            int kw = (kt + 1) << 6;
            async16(w0p + kw, &Ws[cur ^ 1][lb0]);
            async16(w1p + kw, &Ws[cur ^ 1][lb1]);
        }
#pragma unroll
        for (int ks = 0; ks < 2; ++ks) {
            int p8 = (((ks << 2) + koct) ^ sw) << 3;
            bf16x8 a  = *(const bf16x8*)&As[cur][(((wid << 4) + lrow) << 6) + p8];
            bf16x8 b0 = *(const bf16x8*)&Ws[cur][(lrow << 6) + p8];
            bf16x8 b1 = *(const bf16x8*)&Ws[cur][((16 + lrow) << 6) + p8];
            bf16x8 b2 = *(const bf16x8*)&Ws[cur][((32 + lrow) << 6) + p8];
            bf16x8 b3 = *(const bf16x8*)&Ws[cur][((48 + lrow) << 6) + p8];
            acc[0] = __builtin_amdgcn_mfma_f32_16x16x32_bf16(a, b0, acc[0], 0, 0, 0);
            acc[1] = __builtin_amdgcn_mfma_f32_16x16x32_bf16(a, b1, acc[1], 0, 0, 0);
            acc[2] = __builtin_amdgcn_mfma_f32_16x16x32_bf16(a, b2, acc[2], 0, 0, 0);
            acc[3] = __builtin_amdgcn_mfma_f32_16x16x32_bf16(a, b3, acc[3], 0, 0, 0);
        }
        __syncthreads();
    }
    int w0_ = (wid << 4) + (koct << 2);
#pragma unroll
    for (int nf = 0; nf < 4; ++nf) {
        int col = n0 + (nf << 4) + lrow;
        float sc = scsf[col], sf = scsf[192 + col];
        float4 o;
        o.x = fmaxf(acc[nf][0] * sc + sf, 0.f);
        o.y = fmaxf(acc[nf][1] * sc + sf, 0.f);
        o.z = fmaxf(acc[nf][2] * sc + sf, 0.f);
        o.w = fmaxf(acc[nf][3] * sc + sf, 0.f);
        *(float4*)&out[((size_t)(b * Cn + col) << 12) + (h << 6) + w0_] = o;
    }
}

// ----------------------------------------------------------------
extern "C" void kernel_launch(void* const* d_in, const int* in_sizes, int n_in,
                              void* d_out, int out_size, void* d_ws, size_t ws_size,
                              hipStream_t stream) {
    const float* x    = (const float*)d_in[0];
    const float* lnw  = (const float*)d_in[1];
    const float* lnb  = (const float*)d_in[2];
    const float* inpw = (const float*)d_in[3];
    const float* cw   = (const float*)d_in[4];
    const float* cb   = (const float*)d_in[5];
    const float* xpw  = (const float*)d_in[6];
    const float* dtw  = (const float*)d_in[7];
    const float* dtb  = (const float*)d_in[8];
    const float* alog = (const float*)d_in[9];
    const float* Dp   = (const float*)d_in[10];
    const float* Wo   = (const float*)d_in[11];
    const float* rfw  = (const float*)d_in[12];
    const float* rfb  = (const float*)d_in[13];
    const float* bnw  = (const float*)d_in[14];
    const float* bnb  = (const float*)d_in[15];
    const float* bnm  = (const float*)d_in[16];
    const float* bnv  = (const float*)d_in[17];

    float* ws = (float*)d_ws;
    u16* tn_bf    = (u16*)ws;
    float* hstart = ws + 1572864;
    u16* xz       = (u16*)(ws + 3145728);
    u16* xt_bf    = (u16*)(ws + 9437184);
    u32* dedux    = (u32*)(ws + 12582912);
    float* bc     = ws + 18874368;
    u16* agate    = (u16*)(ws + 19398656);
    float* chunkA = ws + 22544384;
    float* chunkH = ws + 24117248;
    u16* wcv2     = (u16*)(ws + 25690112);
    u16* wcomb_bf = (u16*)(ws + 25856000);
    u16* inpw_bf  = (u16*)(ws + 25942016);
    u16* wo_bf    = (u16*)(ws + 26015744);
    float* scsf   = ws + 26052608;
    u16* t2pad    = (u16*)(ws + 26053120);

    hipMemsetAsync(t2pad, 0, (size_t)Bn * HP2 * Cn * sizeof(u16), stream);
    k_prep<<<2834, 256, 0, stream>>>(rfw, xpw, dtw, inpw, Wo, rfb, bnw, bnb, bnm, bnv,
                                     wcv2, wcomb_bf, inpw_bf, wo_bf, scsf);
    k_ln<<<Bn * (Ln / 64), 256, 0, stream>>>(x, lnw, lnb, tn_bf);
    k_gemm3<Cn, 3, 0, 12, E2><<<(Bn * Ln / 64) * 12, 256, 0, stream>>>(
        tn_bf, inpw_bf, nullptr, nullptr, xz, nullptr);
    k_conv1d<<<(Bn * Ln * (DIn / 4)) / 256, 256, 0, stream>>>(xz, cw, cb, xt_bf);
    k_gemm3<DIn, 6, 1, 7, 0><<<(Bn * Ln / 64) * 7, 256, 0, stream>>>(
        xt_bf, wcomb_bf, dtb, xt_bf, dedux, bc);
    k_scan1<<<dim3(DIn / 16, NCn, Bn), 256, 0, stream>>>(dedux, bc, alog, chunkA, chunkH);
    k_scan15<<<dim3(DIn / 16, Bn), 256, 0, stream>>>(chunkA, chunkH, hstart);
    k_scan2<<<dim3(DIn / 16, NCn, Bn), 256, 0, stream>>>(dedux, bc, alog, hstart,
                                                         xt_bf, xz, Dp, agate);
    k_gemm3<DIn, 6, 2, 3, Cn><<<(Bn * Ln / 64) * 3, 256, 0, stream>>>(
        agate, wo_bf, x, nullptr, (void*)t2pad, nullptr);
    k_conv3g<<<768, 256, 0, stream>>>(t2pad, wcv2, scsf, (float*)d_out);
}

// Round 13
// 181.142 us; speedup vs baseline: 1.1350x; 1.0041x over previous
//
#include <hip/hip_runtime.h>

// MambaSkipConnection: B=4, C=192, H=W=64 (L=4096), DI=384, N=16, RK=12, DCONV=4
// Round 13: hipMemsetAsync(t2pad) (40us runtime fill kernel!) replaced by k_zpad
// zeroing only the 260-position halo ring (~400 KB). Rest identical to round 12.

#define Bn 4
#define Cn 192
#define Hn 64
#define Wn 64
#define Ln 4096
#define DIn 384
#define Nst 16
#define RK 12
#define E2 768
#define NCn 64
#define EPSf 1e-5f
#define HP 66
#define HP2 4356   // 66*66

typedef __bf16 bf16x8 __attribute__((ext_vector_type(8)));
typedef float f32x4 __attribute__((ext_vector_type(4)));
typedef unsigned short u16;
typedef unsigned int u32;

static __device__ __forceinline__ float sigmoidf_(float v) {
    return 1.f / (1.f + __expf(-v));
}
static __device__ __forceinline__ float softplusf_(float v) {
    return v > 15.f ? v : __logf(1.f + __expf(v));
}
static __device__ __forceinline__ u16 f2bf(float f) {
    u32 u = __float_as_uint(f);
    u32 r = (u + 0x7FFFu + ((u >> 16) & 1u)) >> 16;
    return (u16)r;
}
static __device__ __forceinline__ float bf2f(u16 v) {
    return __uint_as_float(((u32)v) << 16);
}
static __device__ __forceinline__ float fexp2(float x) {
#if __has_builtin(__builtin_amdgcn_exp2f)
    return __builtin_amdgcn_exp2f(x);
#else
    return __expf(x * 0.69314718056f);
#endif
}
static __device__ __forceinline__ float quad_sum_dpp(float p) {
    float t, r;
    asm volatile("v_add_f32 %0, %1, %1 quad_perm:[1,0,3,2] row_mask:0xf bank_mask:0xf"
                 : "=&v"(t) : "v"(p));
    asm volatile("v_add_f32 %0, %1, %1 quad_perm:[2,3,0,1] row_mask:0xf bank_mask:0xf"
                 : "=&v"(r) : "v"(t));
    return r;
}
static __device__ __forceinline__ void async16(const u16* g, u16* l) {
    __builtin_amdgcn_global_load_lds((__attribute__((address_space(1))) void*)g,
                                     (__attribute__((address_space(3))) void*)l, 16, 0, 0);
}

// ---------------------------------------------------------------- K-1: zero the halo ring of t2pad
// positions: row 0 (66), row 65 (66), col 0 & 65 for rows 1..64 (128) = 260 per image.
// each position = 192 u16 = 24 uint4 chunks. total = 4*260*24 = 24960 chunks.
__global__ __launch_bounds__(256) void k_zpad(u16* __restrict__ t2pad) {
    int g = blockIdx.x * 256 + threadIdx.x;
    if (g >= Bn * 260 * 24) return;
    int chunk = g % 24;
    int pos = g / 24;
    int b = pos / 260;
    int p = pos - b * 260;
    int cell;
    if (p < 66) cell = p;                        // top row
    else if (p < 132) cell = 65 * HP + (p - 66); // bottom row
    else if (p < 196) cell = (p - 132 + 1) * HP;         // left col rows 1..64
    else cell = (p - 196 + 1) * HP + 65;                 // right col rows 1..64
    *(uint4*)&t2pad[((size_t)b * HP2 + cell) * Cn + chunk * 8] = make_uint4(0u, 0u, 0u, 0u);
}

// ---------------------------------------------------------------- K0: weight prep
__global__ __launch_bounds__(256) void k_prep(const float* __restrict__ rfw,
                                              const float* __restrict__ xpw,
                                              const float* __restrict__ dtw,
                                              const float* __restrict__ inpw,
                                              const float* __restrict__ Wo,
                                              const float* __restrict__ rfb,
                                              const float* __restrict__ bnw,
                                              const float* __restrict__ bnb,
                                              const float* __restrict__ bnm,
                                              const float* __restrict__ bnv,
                                              u16* __restrict__ wcv2,
                                              u16* __restrict__ wcomb_bf,
                                              u16* __restrict__ inpw_bf,
                                              u16* __restrict__ wo_bf,
                                              float* __restrict__ scsf) {
    int g = blockIdx.x * 256 + threadIdx.x;
    if (g < 331776) {
        int co = g / 1728;
        int rem = g - co * 1728;
        int tap = rem / Cn, ci = rem - tap * Cn;
        wcv2[g] = f2bf(rfw[((size_t)co * Cn + ci) * 9 + tap]);
    } else if (g < 503808) {
        int i = g - 331776;
        int row = i / 384, k = i - row * 384;
        float v = 0.f;
        if (row < 384) {
#pragma unroll
            for (int r = 0; r < RK; ++r)
                v = fmaf(dtw[row * RK + r], xpw[r * 384 + k], v);
        } else if (row < 416) {
            v = xpw[(RK + row - 384) * 384 + k];
        }
        wcomb_bf[i] = f2bf(v);
    } else if (g < 651264) {
        int i = g - 503808;
        inpw_bf[i] = f2bf(inpw[i]);
    } else if (g < 724992) {
        int i = g - 651264;
        wo_bf[i] = f2bf(Wo[i]);
    } else if (g < 725376) {
        int i = g - 724992;
        if (i < 192) {
            scsf[i] = bnw[i] * rsqrtf(bnv[i] + EPSf);
        } else {
            int c = i - 192;
            float sc = bnw[c] * rsqrtf(bnv[c] + EPSf);
            scsf[i] = (rfb[c] - bnm[c]) * sc + bnb[c];
        }
    }
}

// ---------------------------------------------------------------- K1: LayerNorm -> bf16 tokens
__global__ __launch_bounds__(256) void k_ln(const float* __restrict__ x,
                                            const float* __restrict__ lnw,
                                            const float* __restrict__ lnb,
                                            u16* __restrict__ tn_bf) {
    __shared__ float tile[Cn][65];
    __shared__ float red[2][4][64];
    __shared__ float mean_s[64], rstd_s[64];
    int b = blockIdx.x >> 6;
    int l0 = (blockIdx.x & 63) << 6;
    int tid = threadIdx.x;
    for (int idx = tid; idx < Cn * 64; idx += 256) {
        int c = idx >> 6, ll = idx & 63;
        tile[c][ll] = x[((size_t)(b * Cn + c) << 12) + l0 + ll];
    }
    __syncthreads();
    int ll = tid & 63, grp = tid >> 6;
    float s = 0.f, s2 = 0.f;
    for (int c = grp * 48; c < grp * 48 + 48; ++c) {
        float v = tile[c][ll];
        s += v; s2 += v * v;
    }
    red[0][grp][ll] = s; red[1][grp][ll] = s2;
    __syncthreads();
    if (tid < 64) {
        float m = red[0][0][tid] + red[0][1][tid] + red[0][2][tid] + red[0][3][tid];
        float q = red[1][0][tid] + red[1][1][tid] + red[1][2][tid] + red[1][3][tid];
        m *= (1.f / Cn);
        float var = q * (1.f / Cn) - m * m;
        mean_s[tid] = m;
        rstd_s[tid] = rsqrtf(var + EPSf);
    }
    __syncthreads();
    for (int idx = tid; idx < 64 * Cn; idx += 256) {
        int t = idx / Cn, c = idx - t * Cn;
        float v = (tile[c][t] - mean_s[t]) * rstd_s[t] * lnw[c] + lnb[c];
        tn_bf[(size_t)(b * Ln + l0 + t) * Cn + c] = f2bf(v);
    }
}

// ---------------------------------------------------------------- K2: bf16 GEMM (BM=BN=64, BK=64, async dbuf)
template <int K, int KT, int EPI, int NB, int LDO>
__global__ __launch_bounds__(256) void k_gemm3(const u16* __restrict__ A,
                                               const u16* __restrict__ W,
                                               const float* __restrict__ auxf,
                                               const u16* __restrict__ auxb,
                                               void* __restrict__ out1,
                                               float* __restrict__ out2) {
    __shared__ __align__(16) u16 As[2][64 * 64];
    __shared__ __align__(16) u16 Ws[2][64 * 64];
    int bid = blockIdx.x;
    int q = gridDim.x >> 3;
    int wk = (bid & 7) * q + (bid >> 3);
    int n0 = (wk % NB) << 6;
    int m0 = (wk / NB) << 6;
    int tid = threadIdx.x;
    int wid = tid >> 6, lane = tid & 63;
    int lrow = lane & 15, koct = lane >> 4;
    int sw = lrow & 7;
    int i0 = (wid << 7) + lane;
    int r0 = i0 >> 3, g0 = (i0 & 7) ^ (r0 & 7);
    int i1 = i0 + 64;
    int r1 = i1 >> 3, g1 = (i1 & 7) ^ (r1 & 7);
    const u16* a0p = A + (size_t)(m0 + r0) * K + g0 * 8;
    const u16* a1p = A + (size_t)(m0 + r1) * K + g1 * 8;
    const u16* w0p = W + (size_t)(n0 + r0) * K + g0 * 8;
    const u16* w1p = W + (size_t)(n0 + r1) * K + g1 * 8;
    int lb0 = (wid << 7) << 3;
    int lb1 = lb0 + 512;
    f32x4 acc[4];
#pragma unroll
    for (int j = 0; j < 4; ++j) acc[j] = (f32x4){0.f, 0.f, 0.f, 0.f};

    async16(a0p, &As[0][lb0]); async16(a1p, &As[0][lb1]);
    async16(w0p, &Ws[0][lb0]); async16(w1p, &Ws[0][lb1]);
    __syncthreads();
    for (int kt = 0; kt < KT; ++kt) {
        int cur = kt & 1;
        if (kt + 1 < KT) {
            int kk = (kt + 1) << 6;
            async16(a0p + kk, &As[cur ^ 1][lb0]);
            async16(a1p + kk, &As[cur ^ 1][lb1]);
            async16(w0p + kk, &Ws[cur ^ 1][lb0]);
            async16(w1p + kk, &Ws[cur ^ 1][lb1]);
        }
#pragma unroll
        for (int ks = 0; ks < 2; ++ks) {
            int p8 = (((ks << 2) + koct) ^ sw) << 3;
            bf16x8 a  = *(const bf16x8*)&As[cur][(((wid << 4) + lrow) << 6) + p8];
            bf16x8 b0 = *(const bf16x8*)&Ws[cur][(lrow << 6) + p8];
            bf16x8 b1 = *(const bf16x8*)&Ws[cur][((16 + lrow) << 6) + p8];
            bf16x8 b2 = *(const bf16x8*)&Ws[cur][((32 + lrow) << 6) + p8];
            bf16x8 b3 = *(const bf16x8*)&Ws[cur][((48 + lrow) << 6) + p8];
            acc[0] = __builtin_amdgcn_mfma_f32_16x16x32_bf16(a, b0, acc[0], 0, 0, 0);
            acc[1] = __builtin_amdgcn_mfma_f32_16x16x32_bf16(a, b1, acc[1], 0, 0, 0);
            acc[2] = __builtin_amdgcn_mfma_f32_16x16x32_bf16(a, b2, acc[2], 0, 0, 0);
            acc[3] = __builtin_amdgcn_mfma_f32_16x16x32_bf16(a, b3, acc[3], 0, 0, 0);
        }
        __syncthreads();
    }
    int mrow = m0 + (wid << 4) + (koct << 2);
#pragma unroll
    for (int nf = 0; nf < 4; ++nf) {
        int col = n0 + (nf << 4) + lrow;
        if constexpr (EPI == 0) {
            u16* o = (u16*)out1;
#pragma unroll
            for (int r = 0; r < 4; ++r)
                o[(size_t)(mrow + r) * LDO + col] = f2bf(acc[nf][r]);
        } else if constexpr (EPI == 1) {
            if (col < 384) {
                float dtbc = auxf[col];
                u32* dedux = (u32*)out1;
#pragma unroll
                for (int r = 0; r < 4; ++r) {
                    int m = mrow + r;
                    float de = softplusf_(acc[nf][r] + dtbc);
                    float u = bf2f(auxb[(size_t)m * DIn + col]);
                    dedux[(size_t)m * DIn + col] = (u32)f2bf(de) | ((u32)f2bf(de * u) << 16);
                }
            } else if (col < 416) {
#pragma unroll
                for (int r = 0; r < 4; ++r)
                    out2[(size_t)(mrow + r) * 32 + (col - 384)] = acc[nf][r];
            }
        } else {
            u16* t2 = (u16*)out1;
#pragma unroll
            for (int r = 0; r < 4; ++r) {
                int m = mrow + r;
                int b = m >> 12, l = m & 4095;
                int h = l >> 6, w = l & 63;
                float v = acc[nf][r] + auxf[((size_t)(b * Cn + col) << 12) + l];
                t2[(size_t)(b * HP2 + (h + 1) * HP + (w + 1)) * Cn + col] = f2bf(v);
            }
        }
    }
}

// ---------------------------------------------------------------- K3: causal depthwise conv1d + SiLU
__global__ __launch_bounds__(256) void k_conv1d(const u16* __restrict__ xz,
                                                const float* __restrict__ cw,
                                                const float* __restrict__ cb,
                                                u16* __restrict__ xt_bf) {
    int g = blockIdx.x * 256 + threadIdx.x;
    int m = g / 96, dq = g - m * 96;
    int d = dq << 2;
    int l = m & (Ln - 1);
    float w_[4][4];
    *(float4*)&w_[0][0] = *(const float4*)&cw[(d + 0) << 2];
    *(float4*)&w_[1][0] = *(const float4*)&cw[(d + 1) << 2];
    *(float4*)&w_[2][0] = *(const float4*)&cw[(d + 2) << 2];
    *(float4*)&w_[3][0] = *(const float4*)&cw[(d + 3) << 2];
    float4 bv = *(const float4*)&cb[d];
    float o_[4] = {bv.x, bv.y, bv.z, bv.w};
    const u16* base = xz + (size_t)m * E2 + d;
#pragma unroll
    for (int j = 0; j < 4; ++j) {
        if (l >= j) {
            ushort4 in4 = *(const ushort4*)(base - (size_t)j * E2);
            o_[0] += bf2f(in4.x) * w_[0][3 - j];
            o_[1] += bf2f(in4.y) * w_[1][3 - j];
            o_[2] += bf2f(in4.z) * w_[2][3 - j];
            o_[3] += bf2f(in4.w) * w_[3][3 - j];
        }
    }
    ushort4 rb;
    rb.x = f2bf(o_[0] * sigmoidf_(o_[0]));
    rb.y = f2bf(o_[1] * sigmoidf_(o_[1]));
    rb.z = f2bf(o_[2] * sigmoidf_(o_[2]));
    rb.w = f2bf(o_[3] * sigmoidf_(o_[3]));
    *(ushort4*)&xt_bf[(size_t)m * DIn + d] = rb;
}

// ---------------------------------------------------------------- K6a: scan pass 1 (1 barrier/sub, LDS ping-pong)
__global__ __launch_bounds__(256) void k_scan1(const u32* __restrict__ dedux,
                                               const float* __restrict__ bc,
                                               const float* __restrict__ alog,
                                               float* __restrict__ chunkA,
                                               float* __restrict__ chunkH) {
    __shared__ __align__(16) float ds_de[2][16][20], ds_dux[2][16][20], ds_bt[2][16][20];
    int dg = blockIdx.x, c = blockIdx.y, b = blockIdx.z;
    int tid = threadIdx.x;
    int dl = tid >> 4, n = tid & 15;
    int trow = dl, dd = n;
    float Av2 = -__expf(alog[(dg * 16 + dl) * Nst + n]) * 1.44269504f;
    float h = 0.f, sde = 0.f;
    int row0 = b * Ln + c * 64 + trow;
    u32 vN = dedux[(size_t)row0 * DIn + dg * 16 + dd];
    float bN = bc[(size_t)row0 * 32 + dd];
    for (int sub = 0; sub < 4; ++sub) {
        int bs = sub & 1;
        ds_de[bs][dd][trow] = bf2f((u16)(vN & 0xffffu));
        ds_dux[bs][dd][trow] = bf2f((u16)(vN >> 16));
        ds_bt[bs][dd][trow] = bN;
        __syncthreads();
        if (sub < 3) {
            int row = row0 + (sub + 1) * 16;
            vN = dedux[(size_t)row * DIn + dg * 16 + dd];
            bN = bc[(size_t)row * 32 + dd];
        }
#pragma unroll
        for (int t4 = 0; t4 < 4; ++t4) {
            f32x4 de4 = *(const f32x4*)&ds_de[bs][dl][t4 * 4];
            f32x4 dux4 = *(const f32x4*)&ds_dux[bs][dl][t4 * 4];
            f32x4 bb4 = *(const f32x4*)&ds_bt[bs][n][t4 * 4];
#pragma unroll
            for (int j = 0; j < 4; ++j) {
                float a = fexp2(de4[j] * Av2);
                sde += de4[j];
                h = fmaf(a, h, dux4[j] * bb4[j]);
            }
        }
    }
    size_t base = (size_t)(b * NCn + c) * (DIn * Nst) + dg * 256;
    chunkA[base + tid] = fexp2(Av2 * sde);
    chunkH[base + tid] = h;
}

// ---------------------------------------------------------------- K6b: scan pass 1.5
__global__ __launch_bounds__(256) void k_scan15(const float* __restrict__ chunkA,
                                                const float* __restrict__ chunkH,
                                                float* __restrict__ hstart) {
    int dg = blockIdx.x, b = blockIdx.y;
    int tid = threadIdx.x;
    size_t off = (size_t)b * NCn * (DIn * Nst) + dg * 256 + tid;
    float h = 0.f;
    for (int c0 = 0; c0 < NCn; c0 += 8) {
        float Ar[8], Hr[8];
#pragma unroll
        for (int j = 0; j < 8; ++j) {
            Ar[j] = chunkA[off + (size_t)(c0 + j) * (DIn * Nst)];
            Hr[j] = chunkH[off + (size_t)(c0 + j) * (DIn * Nst)];
        }
#pragma unroll
        for (int j = 0; j < 8; ++j) {
            hstart[off + (size_t)(c0 + j) * (DIn * Nst)] = h;
            h = fmaf(Ar[j], h, Hr[j]);
        }
    }
}

// ---------------------------------------------------------------- K6c: scan pass 2 (1 barrier/sub, deferred gate)
__global__ __launch_bounds__(256) void k_scan2(const u32* __restrict__ dedux,
                                               const float* __restrict__ bc,
                                               const float* __restrict__ alog,
                                               const float* __restrict__ hstart,
                                               const u16* __restrict__ xt_bf,
                                               const u16* __restrict__ xz,
                                               const float* __restrict__ Dp,
                                               u16* __restrict__ agate) {
    __shared__ __align__(16) float ds_de[2][16][20], ds_dux[2][16][20];
    __shared__ __align__(16) float ds_bt[2][16][20], ds_ct[2][16][20];
    __shared__ __align__(16) float pq[2][16][16][4];
    int dg = blockIdx.x, c = blockIdx.y, b = blockIdx.z;
    int tid = threadIdx.x;
    int dl = tid >> 4, n = tid & 15;
    int trow = dl, dd = n;
    int aq = n >> 2, bq = n & 3;
    float Av2 = -__expf(alog[(dg * 16 + dl) * Nst + n]) * 1.44269504f;
    float Dr = Dp[dg * 16 + dd];
    float msk[4];
#pragma unroll
    for (int j = 0; j < 4; ++j) msk[j] = (bq == j) ? 1.f : 0.f;
    size_t base = (size_t)(b * NCn + c) * (DIn * Nst) + dg * 256;
    float h = hstart[base + tid];
    int row0 = b * Ln + c * 64 + trow;
    int dgoff = dg * 16 + dd;
    u32 vN = dedux[(size_t)row0 * DIn + dgoff];
    float bN = bc[(size_t)row0 * 32 + dd];
    float cN = bc[(size_t)row0 * 32 + 16 + dd];
    u16 uN = xt_bf[(size_t)row0 * DIn + dgoff];
    u16 zN = xz[(size_t)row0 * E2 + DIn + dgoff];
    float pu = 0.f, pz = 0.f;
    int prow = row0;
    for (int sub = 0; sub < 4; ++sub) {
        int bs = sub & 1;
        int row = row0 + sub * 16;
        ds_de[bs][dd][trow] = bf2f((u16)(vN & 0xffffu));
        ds_dux[bs][dd][trow] = bf2f((u16)(vN >> 16));
        ds_bt[bs][dd][trow] = bN;
        ds_ct[bs][dd][trow] = cN;
        float uu = bf2f(uN), zz = bf2f(zN);
        __syncthreads();
        if (sub < 3) {
            int rown = row0 + (sub + 1) * 16;
            vN = dedux[(size_t)rown * DIn + dgoff];
            bN = bc[(size_t)rown * 32 + dd];
            cN = bc[(size_t)rown * 32 + 16 + dd];
            uN = xt_bf[(size_t)rown * DIn + dgoff];
            zN = xz[(size_t)rown * E2 + DIn + dgoff];
        }
        if (sub > 0) {
            f32x4 p4 = *(const f32x4*)&pq[bs ^ 1][trow][dd][0];
            float y = (p4[0] + p4[1]) + (p4[2] + p4[3]);
            float ga = (y + pu * Dr) * (pz * sigmoidf_(pz));
            agate[(size_t)prow * DIn + dgoff] = f2bf(ga);
        }
        float P[4] = {0.f, 0.f, 0.f, 0.f};
#pragma unroll
        for (int t4 = 0; t4 < 4; ++t4) {
            f32x4 de4 = *(const f32x4*)&ds_de[bs][dl][t4 * 4];
            f32x4 dux4 = *(const f32x4*)&ds_dux[bs][dl][t4 * 4];
            f32x4 bb4 = *(const f32x4*)&ds_bt[bs][n][t4 * 4];
            f32x4 ct4 = *(const f32x4*)&ds_ct[bs][n][t4 * 4];
#pragma unroll
            for (int j = 0; j < 4; ++j) {
                float a = fexp2(de4[j] * Av2);
                h = fmaf(a, h, dux4[j] * bb4[j]);
                float p = quad_sum_dpp(h * ct4[j]);
                P[t4] = fmaf(msk[j], p, P[t4]);
            }
        }
#pragma unroll
        for (int tt = 0; tt < 4; ++tt)
            pq[bs][tt * 4 + bq][dl][aq] = P[tt];
        pu = uu; pz = zz; prow = row;
    }
    __syncthreads();
    {
        f32x4 p4 = *(const f32x4*)&pq[1][trow][dd][0];
        float y = (p4[0] + p4[1]) + (p4[2] + p4[3]);
        float ga = (y + pu * Dr) * (pz * sigmoidf_(pz));
        agate[(size_t)prow * DIn + dgoff] = f2bf(ga);
    }
}

// ---------------------------------------------------------------- K8: conv3x3 as padded implicit GEMM (K=1728)
__global__ __launch_bounds__(256) void k_conv3g(const u16* __restrict__ t2pad,
                                                const u16* __restrict__ wcv2,
                                                const float* __restrict__ scsf,
                                                float* __restrict__ out) {
    __shared__ __align__(16) u16 As[2][64 * 64];
    __shared__ __align__(16) u16 Ws[2][64 * 64];
    int bid = blockIdx.x;
    int q = gridDim.x >> 3;
    int wk = (bid & 7) * q + (bid >> 3);
    int n0 = (wk % 3) << 6;
    int rowid = wk / 3;
    int b = rowid >> 6, h = rowid & 63;
    int tid = threadIdx.x;
    int wid = tid >> 6, lane = tid & 63;
    int lrow = lane & 15, koct = lane >> 4;
    int sw = lrow & 7;
    int i0 = (wid << 7) + lane;
    int r0 = i0 >> 3, g0 = (i0 & 7) ^ (r0 & 7);
    int i1 = i0 + 64;
    int r1 = i1 >> 3, g1 = (i1 & 7) ^ (r1 & 7);
    const u16* Abase = t2pad + (size_t)(b * HP2 + (h + 1) * HP + 1) * Cn;
    const u16* a0p = Abase + r0 * Cn + g0 * 8;
    const u16* a1p = Abase + r1 * Cn + g1 * 8;
    const u16* w0p = wcv2 + (size_t)(n0 + r0) * 1728 + g0 * 8;
    const u16* w1p = wcv2 + (size_t)(n0 + r1) * 1728 + g1 * 8;
    int lb0 = (wid << 7) << 3;
    int lb1 = lb0 + 512;
    const int tapoff[9] = {-HP - 1, -HP, -HP + 1, -1, 0, 1, HP - 1, HP, HP + 1};
    f32x4 acc[4];
#pragma unroll
    for (int j = 0; j < 4; ++j) acc[j] = (f32x4){0.f, 0.f, 0.f, 0.f};

    {
        int koff = tapoff[0] * Cn;
        async16(a0p + koff, &As[0][lb0]); async16(a1p + koff, &As[0][lb1]);
        async16(w0p, &Ws[0][lb0]); async16(w1p, &Ws[0][lb1]);
    }
    __syncthreads();
    for (int kt = 0; kt < 27; ++kt) {
        int cur = kt & 1;
        if (kt + 1 < 27) {
            int t = (kt + 1) / 3;
            int koff = tapoff[t] * Cn + (((kt + 1) - t * 3) << 6);
            async16(a0p + koff, &As[cur ^ 1][lb0]);
            async16(a1p + koff, &As[cur ^ 1][lb1]);
            int kw = (kt + 1) << 6;
            async16(w0p + kw, &Ws[cur ^ 1][lb0]);
            async16(w1p + kw, &Ws[cur ^ 1][lb1]);
        }
#pragma unroll
        for (int ks = 0; ks < 2; ++ks) {
            int p8 = (((ks << 2) + koct) ^ sw) << 3;
            bf16x8 a  = *(const bf16x8*)&As[cur][(((wid << 4) + lrow) << 6) + p8];
            bf16x8 b0 = *(const bf16x8*)&Ws[cur][(lrow << 6) + p8];
            bf16x8 b1 = *(const bf16x8*)&Ws[cur][((16 + lrow) << 6) + p8];
            bf16x8 b2 = *(const bf16x8*)&Ws[cur][((32 + lrow) << 6) + p8];
            bf16x8 b3 = *(const bf16x8*)&Ws[cur][((48 + lrow) << 6) + p8];
            acc[0] = __builtin_amdgcn_mfma_f32_16x16x32_bf16(a, b0, acc[0], 0, 0, 0);
            acc[1] = __builtin_amdgcn_mfma_f32_16x16x32_bf16(a, b1, acc[1], 0, 0, 0);
            acc[2] = __builtin_amdgcn_mfma_f32_16x16x32_bf16(a, b2, acc[2], 0, 0, 0);
            acc[3] = __builtin_amdgcn_mfma_f32_16x16x32_bf16(a, b3, acc[3], 0, 0, 0);
        }
        __syncthreads();
    }
    int w0_ = (wid << 4) + (koct << 2);
#pragma unroll
    for (int nf = 0; nf < 4; ++nf) {
        int col = n0 + (nf << 4) + lrow;
        float sc = scsf[col], sf = scsf[192 + col];
        float4 o;
        o.x = fmaxf(acc[nf][0] * sc + sf, 0.f);
        o.y = fmaxf(acc[nf][1] * sc + sf, 0.f);
        o.z = fmaxf(acc[nf][2] * sc + sf, 0.f);
        o.w = fmaxf(acc[nf][3] * sc + sf, 0.f);
        *(float4*)&out[((size_t)(b * Cn + col) << 12) + (h << 6) + w0_] = o;
    }
}

// ----------------------------------------------------------------
extern "C" void kernel_launch(void* const* d_in, const int* in_sizes, int n_in,
                              void* d_out, int out_size, void* d_ws, size_t ws_size,
                              hipStream_t stream) {
    const float* x    = (const float*)d_in[0];
    const float* lnw  = (const float*)d_in[1];
    const float* lnb  = (const float*)d_in[2];
    const float* inpw = (const float*)d_in[3];
    const float* cw   = (const float*)d_in[4];
    const float* cb   = (const float*)d_in[5];
    const float* xpw  = (const float*)d_in[6];
    const float* dtw  = (const float*)d_in[7];
    const float* dtb  = (const float*)d_in[8];
    const float* alog = (const float*)d_in[9];
    const float* Dp   = (const float*)d_in[10];
    const float* Wo   = (const float*)d_in[11];
    const float* rfw  = (const float*)d_in[12];
    const float* rfb  = (const float*)d_in[13];
    const float* bnw  = (const float*)d_in[14];
    const float* bnb  = (const float*)d_in[15];
    const float* bnm  = (const float*)d_in[16];
    const float* bnv  = (const float*)d_in[17];

    float* ws = (float*)d_ws;
    u16* tn_bf    = (u16*)ws;
    float* hstart = ws + 1572864;
    u16* xz       = (u16*)(ws + 3145728);
    u16* xt_bf    = (u16*)(ws + 9437184);
    u32* dedux    = (u32*)(ws + 12582912);
    float* bc     = ws + 18874368;
    u16* agate    = (u16*)(ws + 19398656);
    float* chunkA = ws + 22544384;
    float* chunkH = ws + 24117248;
    u16* wcv2     = (u16*)(ws + 25690112);
    u16* wcomb_bf = (u16*)(ws + 25856000);
    u16* inpw_bf  = (u16*)(ws + 25942016);
    u16* wo_bf    = (u16*)(ws + 26015744);
    float* scsf   = ws + 26052608;
    u16* t2pad    = (u16*)(ws + 26053120);

    k_zpad<<<(Bn * 260 * 24 + 255) / 256, 256, 0, stream>>>(t2pad);
    k_prep<<<2834, 256, 0, stream>>>(rfw, xpw, dtw, inpw, Wo, rfb, bnw, bnb, bnm, bnv,
                                     wcv2, wcomb_bf, inpw_bf, wo_bf, scsf);
    k_ln<<<Bn * (Ln / 64), 256, 0, stream>>>(x, lnw, lnb, tn_bf);
    k_gemm3<Cn, 3, 0, 12, E2><<<(Bn * Ln / 64) * 12, 256, 0, stream>>>(
        tn_bf, inpw_bf, nullptr, nullptr, xz, nullptr);
    k_conv1d<<<(Bn * Ln * (DIn / 4)) / 256, 256, 0, stream>>>(xz, cw, cb, xt_bf);
    k_gemm3<DIn, 6, 1, 7, 0><<<(Bn * Ln / 64) * 7, 256, 0, stream>>>(
        xt_bf, wcomb_bf, dtb, xt_bf, dedux, bc);
    k_scan1<<<dim3(DIn / 16, NCn, Bn), 256, 0, stream>>>(dedux, bc, alog, chunkA, chunkH);
    k_scan15<<<dim3(DIn / 16, Bn), 256, 0, stream>>>(chunkA, chunkH, hstart);
    k_scan2<<<dim3(DIn / 16, NCn, Bn), 256, 0, stream>>>(dedux, bc, alog, hstart,
                                                         xt_bf, xz, Dp, agate);
    k_gemm3<DIn, 6, 2, 3, Cn><<<(Bn * Ln / 64) * 3, 256, 0, stream>>>(
        agate, wo_bf, x, nullptr, (void*)t2pad, nullptr);
    k_conv3g<<<768, 256, 0, stream>>>(t2pad, wcv2, scsf, (float*)d_out);
}